// Round 2
// baseline (304.484 us; speedup 1.0000x reference)
//
#include <hip/hip_runtime.h>
#include <hip/hip_bf16.h>
#include <cstdint>
#include <cstddef>

#define B_ 16
#define TX_ 256
#define TY_ 2048
#define C_ 80
#define H_ 256
#define NEG_ -1e9f
#define NEG_I (int)0xCE6E6B28   // bit pattern of -1e9f

// one backtrace step at column-in-chunk jb from row ii, using window pair W
// (rows 8p..8p+7) with fallback Wl (rows 8p-8..8p-1).
// Diag bit layout (4 independent carry-push chains in fwd): within each
// 32-bit word (4 rows), row r = byte r; column jb at bit (7-jb). In the u64
// W, rows 8p..8p+3 are the low word, 8p+4..8p+7 the high word, so the bit
// for row ii, col jb sits at ((ii&7)<<3) | (7-jb).
#define BT_STEP(JB)                                                           \
    {                                                                         \
        unsigned bit = ((unsigned)(W >> (((ii & 7) << 3)                      \
                                         | (7 - (JB)))) & 1u)                 \
                     & (unsigned)(ii > 0);                                    \
        ii -= (int)bit;                                                       \
        W = (bit && ((ii & 7) == 7)) ? Wl : W;                                \
    }

// ---------------------------------------------------------------------------
// Kernel 1: logp[b,x,t] = -0.5*( S1 - 2*S2 + T3[x] )/C - 0.5*mean_c(ls[x])
// Register tile: 16 x * 4 t per thread. Also emits transposed logp_t [B,Ty,Tx]
// (into the attn slot of d_out) so MAS reads DP columns coalesced.
// ---------------------------------------------------------------------------
__global__ __launch_bounds__(256) void logp_kernel(
    const float* __restrict__ mu, const float* __restrict__ ls,
    const float* __restrict__ y, float* __restrict__ logp_out,
    float* __restrict__ logp_t)
{
    __shared__ float2 coef[16 * 80];
    __shared__ float  aux[16 * 80];
    __shared__ float  Kx[16];
    __shared__ float  yt[16 * 1028];

    const int tid = threadIdx.x;
    const int t0 = blockIdx.x * 1024;
    const int x0 = blockIdx.y * 16;
    const int b  = blockIdx.z;

    for (int i = tid; i < 16 * 80; i += 256) {
        int c = i >> 4, x = i & 15;
        float m = mu[(size_t)(b * C_ + c) * TX_ + x0 + x];
        float l = ls[(size_t)(b * C_ + c) * TX_ + x0 + x];
        float w = __expf(-2.f * l);
        coef[x * 80 + c] = make_float2(w, -2.f * m * w);
        aux[x * 80 + c]  = fmaf(m * m, w, l);
    }
    __syncthreads();
    if (tid < 16) {
        float s = 0.f;
        for (int c = 0; c < C_; ++c) s += aux[tid * 80 + c];
        Kx[tid] = -0.5f * s / (float)C_;
    }

    float acc[16][4];
#pragma unroll
    for (int x = 0; x < 16; ++x)
#pragma unroll
        for (int r = 0; r < 4; ++r) acc[x][r] = 0.f;

    const float4* y4 = (const float4*)y;
    for (int c0 = 0; c0 < C_; c0 += 16) {
        __syncthreads();
        for (int it = 0; it < 16; ++it) {
            int f = tid + it * 256;
            int t = f >> 2, k = f & 3;
            float4 v = y4[(size_t)(b * TY_ + t0 + t) * 20 + (c0 >> 2) + k];
            yt[(4 * k + 0) * 1028 + t] = v.x;
            yt[(4 * k + 1) * 1028 + t] = v.y;
            yt[(4 * k + 2) * 1028 + t] = v.z;
            yt[(4 * k + 3) * 1028 + t] = v.w;
        }
        __syncthreads();
        for (int cl = 0; cl < 16; ++cl) {
            const float4 yv = *reinterpret_cast<const float4*>(&yt[cl * 1028 + 4 * tid]);
            float4 y2 = make_float4(yv.x * yv.x, yv.y * yv.y, yv.z * yv.z, yv.w * yv.w);
#pragma unroll
            for (int x = 0; x < 16; ++x) {
                float2 f2 = coef[x * 80 + c0 + cl];
                acc[x][0] = fmaf(y2.x, f2.x, fmaf(yv.x, f2.y, acc[x][0]));
                acc[x][1] = fmaf(y2.y, f2.x, fmaf(yv.y, f2.y, acc[x][1]));
                acc[x][2] = fmaf(y2.z, f2.x, fmaf(yv.z, f2.y, acc[x][2]));
                acc[x][3] = fmaf(y2.w, f2.x, fmaf(yv.w, f2.y, acc[x][3]));
            }
        }
    }

#pragma unroll
    for (int x = 0; x < 16; ++x) {
        float kx = Kx[x];
#pragma unroll
        for (int r = 0; r < 4; ++r) acc[x][r] = fmaf(acc[x][r], -0.5f / (float)C_, kx);
        float4 out = make_float4(acc[x][0], acc[x][1], acc[x][2], acc[x][3]);
        *reinterpret_cast<float4*>(
            &logp_out[(size_t)(b * TX_ + x0 + x) * TY_ + t0 + 4 * tid]) = out;
    }
#pragma unroll
    for (int r = 0; r < 4; ++r) {
#pragma unroll
        for (int q = 0; q < 4; ++q) {
            float4 out = make_float4(acc[4 * q + 0][r], acc[4 * q + 1][r],
                                     acc[4 * q + 2][r], acc[4 * q + 3][r]);
            *reinterpret_cast<float4*>(
                &logp_t[(size_t)(b * TY_ + t0 + 4 * tid + r) * TX_ + x0 + 4 * q]) = out;
        }
    }
}

// ---------------------------------------------------------------------------
// Kernel 2a: MAS forward. Single wave per batch, NO LDS, NO barriers.
// Direct global->VGPR column loads, 32-deep software pipeline (counted vmcnt).
// Diag bits: 4 INDEPENDENT carry-push chains (one per row slot), each cmp
// writing its own SGPR pair -> no vcc serialization, no dependency stalls.
// ---------------------------------------------------------------------------
#define PD_ 32   // pipeline depth (columns in flight)

#define DP_STEP(CVAL, KC)                                                     \
    {                                                                         \
        int shi = __builtin_amdgcn_update_dpp(                                \
            NEG_I, __float_as_int(v3), 0x138 /*wave_shr1*/, 0xF, 0xF, false); \
        float sh0 = __int_as_float(shi);                                      \
        unsigned long long t0, t1, t2, t3;                                    \
        asm("v_cmp_gt_f32 %[c0], %[sh], %[v0]\n\t"                            \
            "v_cmp_gt_f32 %[c1], %[v0], %[v1]\n\t"                            \
            "v_cmp_gt_f32 %[c2], %[v1], %[v2]\n\t"                            \
            "v_cmp_gt_f32 %[c3], %[v2], %[v3]\n\t"                            \
            "v_addc_co_u32 %[a0], %[c0], %[a0], %[a0], %[c0]\n\t"             \
            "v_addc_co_u32 %[a1], %[c1], %[a1], %[a1], %[c1]\n\t"             \
            "v_addc_co_u32 %[a2], %[c2], %[a2], %[a2], %[c2]\n\t"             \
            "v_addc_co_u32 %[a3], %[c3], %[a3], %[a3], %[c3]"                 \
            : [a0]"+v"(a0b), [a1]"+v"(a1b), [a2]"+v"(a2b), [a3]"+v"(a3b),     \
              [c0]"=&s"(t0), [c1]"=&s"(t1), [c2]"=&s"(t2), [c3]"=&s"(t3)      \
            : [sh]"v"(sh0), [v0]"v"(v0), [v1]"v"(v1),                         \
              [v2]"v"(v2), [v3]"v"(v3));                                      \
        float m0 = fmaxf(v0, sh0);                                            \
        float m1 = fmaxf(v1, v0);                                             \
        float m2 = fmaxf(v2, v1);                                             \
        float m3 = fmaxf(v3, v2);                                             \
        v0 = m0 + (CVAL).x; v1 = m1 + (CVAL).y;                               \
        v2 = m2 + (CVAL).z; v3 = m3 + (CVAL).w;                               \
        if (((KC) & 7) == 7) {                                                \
            diag[((KC) >> 3) * 64 + lane] =                                   \
                a0b | (a1b << 8) | (a2b << 16) | (a3b << 24);                 \
            a0b = 0u; a1b = 0u; a2b = 0u; a3b = 0u;                           \
        }                                                                     \
    }

__global__ __launch_bounds__(64, 1) void mas_fwd_kernel(
    const float* __restrict__ logp_t, unsigned int* __restrict__ diag_g)
{
    const int lane = threadIdx.x;
    const int b = blockIdx.x;

    const float* colp = logp_t + (size_t)b * TY_ * TX_ + lane * 4;
    unsigned int* diag = diag_g + (size_t)b * (TY_ / 8) * 64;  // [chunk8][word]

    float v0 = (lane == 0) ? 0.f : NEG_, v1 = NEG_, v2 = NEG_, v3 = NEG_;
    unsigned int a0b = 0, a1b = 0, a2b = 0, a3b = 0;

    float4 pre[PD_];
#pragma unroll
    for (int j = 0; j < PD_; ++j)
        pre[j] = *reinterpret_cast<const float4*>(colp + (size_t)j * 256);

    // main loop: process pre[j] (col k0+j), refill with col k0+PD_+j
    for (int k0 = 0; k0 < TY_ - PD_; k0 += PD_) {
        const float* nxt = colp + (size_t)(k0 + PD_) * 256;
#pragma unroll
        for (int j = 0; j < PD_; ++j) {
            float4 c = pre[j];
            pre[j] = *reinterpret_cast<const float4*>(nxt + (size_t)j * 256);
            DP_STEP(c, k0 + j)
        }
    }
    // epilogue: last PD_ columns, no refill
    {
        const int k0 = TY_ - PD_;
#pragma unroll
        for (int j = 0; j < PD_; ++j) {
            float4 c = pre[j];
            DP_STEP(c, k0 + j)
        }
    }
}

// ---------------------------------------------------------------------------
// Kernel 2b: exit-table build. E_c[i] = row after walking chunk c (8 cols)
// entered at row i. grid (16 chunk-groups, 16 b) x 256 thr -> 256 blocks,
// 16 entries/thread, fully parallel across the whole GPU.
// ---------------------------------------------------------------------------
__global__ __launch_bounds__(256) void mas_tab_kernel(
    const unsigned int* __restrict__ diag_g, unsigned char* __restrict__ E_g)
{
    const int t  = threadIdx.x;        // entry row
    const int cg = blockIdx.x;         // chunk group of 16
    const int b  = blockIdx.y;
    const unsigned int* dg = diag_g + (size_t)b * (TY_ / 8) * 64;
    unsigned char* Eb = E_g + (size_t)b * (TY_ / 8) * 256;
    const int p = t >> 3;

    for (int k = 0; k < 16; ++k) {
        const int c = cg * 16 + k;
        unsigned long long W  = *(const unsigned long long*)&dg[c * 64 + 2 * p];
        unsigned long long Wl = p > 0
            ? *(const unsigned long long*)&dg[c * 64 + 2 * (p - 1)] : 0ULL;
        int ii = t;
#pragma unroll
        for (int jb = 7; jb >= 0; --jb) BT_STEP(jb)
        Eb[c * 256 + t] = (unsigned char)ii;
    }
}

// ---------------------------------------------------------------------------
// Kernel 2c: MAS backtrace via exit tables. Serial part is now only the
// 255-step chunk-entry chain (dependent LDS byte reads); emission of all
// 8-column chunks runs in parallel (1 thread/chunk). dr via LDS histogram.
// ---------------------------------------------------------------------------
__global__ __launch_bounds__(256) void mas_bt_kernel(
    const unsigned int* __restrict__ diag_g, const unsigned char* __restrict__ E_g,
    const int* __restrict__ xlen, const int* __restrict__ ylen,
    float* __restrict__ dr_out, int* __restrict__ idx_out)
{
    __shared__ unsigned char E[256 * 256];      // 64 KiB
    __shared__ unsigned char entry_s[256];
    __shared__ int rows_l[TY_];                 // 8 KiB
    __shared__ int cnt_l[TX_];                  // 1 KiB
    const int tid = threadIdx.x;
    const int b = blockIdx.x;
    const int x_len = xlen[b];
    const int y_len = ylen[b];

    cnt_l[tid] = 0;

    // copy E tables global->LDS, coalesced uint4
    const uint4* srcE = (const uint4*)(E_g + (size_t)b * (TY_ / 8) * 256);
    uint4* dstE = (uint4*)E;
#pragma unroll
    for (int it = 0; it < 16; ++it)
        dstE[tid + it * 256] = srcE[tid + it * 256];
    __syncthreads();

    const unsigned int* dg = diag_g + (size_t)b * (TY_ / 8) * 64;
    int* ib = idx_out + (size_t)b * TY_;
    const int jc = (y_len - 1) >> 3;

    if (tid == 0) {
        // partial top chunk (columns y_len-1 .. 8*jc), serial <=8 steps
        int ii = x_len - 1;
        int p = ii >> 3;
        unsigned long long W  = *(const unsigned long long*)&dg[jc * 64 + 2 * p];
        unsigned long long Wl = p > 0
            ? *(const unsigned long long*)&dg[jc * 64 + 2 * (p - 1)] : 0ULL;
        for (int jb = (y_len - 1) & 7; jb >= 0; --jb) {
            int j = 8 * jc + jb;
            ib[j] = ii; rows_l[j] = ii;
            BT_STEP(jb)
        }
        // entry chain over full chunks: 255 dependent LDS byte reads
        int cur = ii;
        for (int c = jc - 1; c >= 0; --c) {
            entry_s[c] = (unsigned char)cur;
            cur = E[c * 256 + cur];
        }
    }
    __syncthreads();

    // parallel emission: one thread per full chunk
    if (tid < jc) {
        const int c = tid;
        int ii = entry_s[c];
        int p = ii >> 3;
        unsigned long long W  = *(const unsigned long long*)&dg[c * 64 + 2 * p];
        unsigned long long Wl = p > 0
            ? *(const unsigned long long*)&dg[c * 64 + 2 * (p - 1)] : 0ULL;
        int r[8];
#pragma unroll
        for (int jb = 7; jb >= 0; --jb) {
            r[jb] = ii;
            BT_STEP(jb)
        }
        *reinterpret_cast<int4*>(&ib[8 * c])     = make_int4(r[0], r[1], r[2], r[3]);
        *reinterpret_cast<int4*>(&ib[8 * c + 4]) = make_int4(r[4], r[5], r[6], r[7]);
        *reinterpret_cast<int4*>(&rows_l[8 * c])     = make_int4(r[0], r[1], r[2], r[3]);
        *reinterpret_cast<int4*>(&rows_l[8 * c + 4]) = make_int4(r[4], r[5], r[6], r[7]);
    }
    __syncthreads();

    // dr[i] = #{ j < y_len : row(j) == i }
    for (int t = tid; t < TY_; t += 256)
        if (t < y_len) atomicAdd(&cnt_l[rows_l[t]], 1);
    __syncthreads();
    dr_out[(size_t)b * TX_ + tid] = (float)cnt_l[tid];
}

// ---------------------------------------------------------------------------
// Kernel 3: emit attn (one-hot path) and o_en_ex (gather of en rows).
// ---------------------------------------------------------------------------
__global__ __launch_bounds__(256) void emit_kernel(
    const float* __restrict__ en, const int* __restrict__ ylen,
    const int* __restrict__ idx_in, float* __restrict__ o_en,
    float* __restrict__ attn)
{
    const int tid = threadIdx.x;
    const int b = blockIdx.x;
    const int r = blockIdx.y;
    const int y_len = ylen[b];
    const int* ib = idx_in + (size_t)b * TY_;

    if (r < 256) {
        const int x = r;
        float* out = attn + ((size_t)b * TX_ + x) * TY_;
        for (int t = tid; t < TY_; t += 256) {
            int ii = ib[t];
            out[t] = (t < y_len && ii == x) ? 1.f : 0.f;
        }
    } else {
        const int h = r - 256;
        __shared__ float enr[256];
        enr[tid] = en[((size_t)b * H_ + h) * TX_ + tid];
        __syncthreads();
        float* out = o_en + ((size_t)b * H_ + h) * TY_;
        for (int t = tid; t < TY_; t += 256) {
            int ii = ib[t];
            bool a = (t < y_len);
            int is = a ? ii : 0;
            out[t] = a ? enr[is] : 0.f;
        }
    }
}

// ---------------------------------------------------------------------------
extern "C" void kernel_launch(void* const* d_in, const int* in_sizes, int n_in,
                              void* d_out, int out_size, void* d_ws, size_t ws_size,
                              hipStream_t stream)
{
    const float* en = (const float*)d_in[0];
    const float* mu = (const float*)d_in[1];
    const float* ls = (const float*)d_in[2];
    const float* y  = (const float*)d_in[3];
    const int* xl   = (const int*)d_in[4];
    const int* yl   = (const int*)d_in[5];

    float* o_en = (float*)d_out;                       // [16,256,2048]
    float* attn = o_en + (size_t)B_ * TX_ * TY_;       // [16,256,2048]
    float* dr   = attn + (size_t)B_ * TX_ * TY_;       // [16,256]
    float* logp = dr + (size_t)B_ * TX_;               // [16,256,2048]

    float* logp_t = attn;                              // scratch in attn slot
    // diag scratch in the o_en slot (1 MB; emit overwrites later)
    unsigned int* diag_g = (unsigned int*)o_en;
    // exit tables E in the logp_t region (dead after mas_fwd; 1 MB)
    unsigned char* E_g = (unsigned char*)logp_t;
    int* idxArr = (int*)d_ws;                          // [16,2048]

    dim3 g1(2, 16, 16);
    logp_kernel<<<g1, 256, 0, stream>>>(mu, ls, y, logp, logp_t);

    mas_fwd_kernel<<<dim3(16), dim3(64), 0, stream>>>(logp_t, diag_g);
    mas_tab_kernel<<<dim3(16, 16), dim3(256), 0, stream>>>(diag_g, E_g);
    mas_bt_kernel<<<dim3(16), dim3(256), 0, stream>>>(diag_g, E_g, xl, yl, dr, idxArr);

    dim3 g3(16, 512);
    emit_kernel<<<g3, 256, 0, stream>>>(en, yl, idxArr, o_en, attn);
}

// Round 3
// 293.398 us; speedup vs baseline: 1.0378x; 1.0378x over previous
//
#include <hip/hip_runtime.h>
#include <hip/hip_bf16.h>
#include <cstdint>
#include <cstddef>

#define B_ 16
#define TX_ 256
#define TY_ 2048
#define C_ 80
#define H_ 256
#define NEG_ -1e9f
#define NEG_I (int)0xCE6E6B28   // bit pattern of -1e9f

// one backtrace step at column-in-chunk jb from row ii, using window pair W
// (rows 8p..8p+7) with fallback Wl (rows 8p-8..8p-1).
// Diag bit layout (4 independent carry-push chains in fwd): within each
// 32-bit word (4 rows), row r = byte r; column jb at bit (7-jb). In the u64
// W, rows 8p..8p+3 are the low word, 8p+4..8p+7 the high word, so the bit
// for row ii, col jb sits at ((ii&7)<<3) | (7-jb).
#define BT_STEP(JB)                                                           \
    {                                                                         \
        unsigned bit = ((unsigned)(W >> (((ii & 7) << 3)                      \
                                         | (7 - (JB)))) & 1u)                 \
                     & (unsigned)(ii > 0);                                    \
        ii -= (int)bit;                                                       \
        W = (bit && ((ii & 7) == 7)) ? Wl : W;                                \
    }

// ---------------------------------------------------------------------------
// Kernel 1: logp[b,x,t] = -0.5*( S1 - 2*S2 + T3[x] )/C - 0.5*mean_c(ls[x])
// Register tile: 16 x * 4 t per thread. Also emits transposed logp_t [B,Ty,Tx]
// (into the attn slot of d_out) so MAS reads DP columns coalesced.
// ---------------------------------------------------------------------------
__global__ __launch_bounds__(256) void logp_kernel(
    const float* __restrict__ mu, const float* __restrict__ ls,
    const float* __restrict__ y, float* __restrict__ logp_out,
    float* __restrict__ logp_t)
{
    __shared__ float2 coef[16 * 80];
    __shared__ float  aux[16 * 80];
    __shared__ float  Kx[16];
    __shared__ float  yt[16 * 1028];

    const int tid = threadIdx.x;
    const int t0 = blockIdx.x * 1024;
    const int x0 = blockIdx.y * 16;
    const int b  = blockIdx.z;

    for (int i = tid; i < 16 * 80; i += 256) {
        int c = i >> 4, x = i & 15;
        float m = mu[(size_t)(b * C_ + c) * TX_ + x0 + x];
        float l = ls[(size_t)(b * C_ + c) * TX_ + x0 + x];
        float w = __expf(-2.f * l);
        coef[x * 80 + c] = make_float2(w, -2.f * m * w);
        aux[x * 80 + c]  = fmaf(m * m, w, l);
    }
    __syncthreads();
    if (tid < 16) {
        float s = 0.f;
        for (int c = 0; c < C_; ++c) s += aux[tid * 80 + c];
        Kx[tid] = -0.5f * s / (float)C_;
    }

    float acc[16][4];
#pragma unroll
    for (int x = 0; x < 16; ++x)
#pragma unroll
        for (int r = 0; r < 4; ++r) acc[x][r] = 0.f;

    const float4* y4 = (const float4*)y;
    for (int c0 = 0; c0 < C_; c0 += 16) {
        __syncthreads();
        for (int it = 0; it < 16; ++it) {
            int f = tid + it * 256;
            int t = f >> 2, k = f & 3;
            float4 v = y4[(size_t)(b * TY_ + t0 + t) * 20 + (c0 >> 2) + k];
            yt[(4 * k + 0) * 1028 + t] = v.x;
            yt[(4 * k + 1) * 1028 + t] = v.y;
            yt[(4 * k + 2) * 1028 + t] = v.z;
            yt[(4 * k + 3) * 1028 + t] = v.w;
        }
        __syncthreads();
        for (int cl = 0; cl < 16; ++cl) {
            const float4 yv = *reinterpret_cast<const float4*>(&yt[cl * 1028 + 4 * tid]);
            float4 y2 = make_float4(yv.x * yv.x, yv.y * yv.y, yv.z * yv.z, yv.w * yv.w);
#pragma unroll
            for (int x = 0; x < 16; ++x) {
                float2 f2 = coef[x * 80 + c0 + cl];
                acc[x][0] = fmaf(y2.x, f2.x, fmaf(yv.x, f2.y, acc[x][0]));
                acc[x][1] = fmaf(y2.y, f2.x, fmaf(yv.y, f2.y, acc[x][1]));
                acc[x][2] = fmaf(y2.z, f2.x, fmaf(yv.z, f2.y, acc[x][2]));
                acc[x][3] = fmaf(y2.w, f2.x, fmaf(yv.w, f2.y, acc[x][3]));
            }
        }
    }

#pragma unroll
    for (int x = 0; x < 16; ++x) {
        float kx = Kx[x];
#pragma unroll
        for (int r = 0; r < 4; ++r) acc[x][r] = fmaf(acc[x][r], -0.5f / (float)C_, kx);
        float4 out = make_float4(acc[x][0], acc[x][1], acc[x][2], acc[x][3]);
        *reinterpret_cast<float4*>(
            &logp_out[(size_t)(b * TX_ + x0 + x) * TY_ + t0 + 4 * tid]) = out;
    }
#pragma unroll
    for (int r = 0; r < 4; ++r) {
#pragma unroll
        for (int q = 0; q < 4; ++q) {
            float4 out = make_float4(acc[4 * q + 0][r], acc[4 * q + 1][r],
                                     acc[4 * q + 2][r], acc[4 * q + 3][r]);
            *reinterpret_cast<float4*>(
                &logp_t[(size_t)(b * TY_ + t0 + 4 * tid + r) * TX_ + x0 + 4 * q]) = out;
        }
    }
}

// ---------------------------------------------------------------------------
// Kernel 2a: MAS forward — FULL INLINE ASM scan.
// One wave per batch. 32-column prefetch buffer hand-allocated in v32..v159
// (4 VGPRs/column). Per column: exactly 20 VALU + 1 VMEM:
//   mov NEG + dpp(shr1)          2   (sh = v3 from lane-1; lane0 keeps NEG)
//   v_cmp_gt x4 (vcc,s[20:25])   4   diag bits, old values
//   v_max x4 (descending, in-place, no temps)                    4
//   v_add x4 (+= c from buffer slot)                             4
//   v_addc carry-push x4 (a = 2a + bit)                          4
//   global_load_dwordx4 (col+32) + v_add_u32 voffset             2
// Counted s_waitcnt vmcnt(24) ONCE per 8 columns (never 0): buffer slot j is
// consumed 32 columns after its load issues; 24 = exact worst-case count of
// younger VMEM ops (verified for first and steady iterations).
// Diag word semantics identical to verified R2 layout (consumers unchanged).
// ---------------------------------------------------------------------------
#define PRO(RQ) \
    "global_load_dwordx4 " RQ ", %[vo], %[sb]\n\t" \
    "v_add_u32 %[vo], 0x400, %[vo]\n\t"

#define COLA(RQ, R0, R1, R2, R3) \
    "v_mov_b32 v28, v31\n\t" \
    "v_mov_b32_dpp v28, %[v3] wave_shr:1 row_mask:0xf bank_mask:0xf\n\t" \
    "v_cmp_gt_f32 vcc, v28, %[v0]\n\t" \
    "v_cmp_gt_f32 s[20:21], %[v0], %[v1]\n\t" \
    "v_cmp_gt_f32 s[22:23], %[v1], %[v2]\n\t" \
    "v_cmp_gt_f32 s[24:25], %[v2], %[v3]\n\t" \
    "v_max_f32 %[v3], %[v2], %[v3]\n\t" \
    "v_max_f32 %[v2], %[v1], %[v2]\n\t" \
    "v_max_f32 %[v1], %[v0], %[v1]\n\t" \
    "v_max_f32 %[v0], v28, %[v0]\n\t" \
    "v_add_f32 %[v0], " R0 ", %[v0]\n\t" \
    "v_add_f32 %[v1], " R1 ", %[v1]\n\t" \
    "v_add_f32 %[v2], " R2 ", %[v2]\n\t" \
    "v_add_f32 %[v3], " R3 ", %[v3]\n\t" \
    "v_addc_co_u32 %[a0], vcc, %[a0], %[a0], vcc\n\t" \
    "v_addc_co_u32 %[a1], s[20:21], %[a1], %[a1], s[20:21]\n\t" \
    "v_addc_co_u32 %[a2], s[22:23], %[a2], %[a2], s[22:23]\n\t" \
    "v_addc_co_u32 %[a3], s[24:25], %[a3], %[a3], s[24:25]\n\t" \
    "global_load_dwordx4 " RQ ", %[vo], %[sb]\n\t" \
    "v_add_u32 %[vo], 0x400, %[vo]\n\t"

#define STOREBLK \
    "v_lshl_or_b32 v29, %[a1], 8, %[a0]\n\t" \
    "v_lshl_or_b32 v29, %[a2], 16, v29\n\t" \
    "v_lshl_or_b32 v29, %[a3], 24, v29\n\t" \
    "global_store_dword %[df], v29, %[db]\n\t" \
    "v_add_u32 %[df], 0x100, %[df]\n\t" \
    "v_mov_b32 %[a0], 0\n\t" \
    "v_mov_b32 %[a1], 0\n\t" \
    "v_mov_b32 %[a2], 0\n\t" \
    "v_mov_b32 %[a3], 0\n\t"

#define WAITG "s_waitcnt vmcnt(24)\n\t"

__global__ __launch_bounds__(64, 1) void mas_fwd_kernel(
    const float* __restrict__ logp_t, unsigned int* __restrict__ diag_g)
{
    const int lane = threadIdx.x;
    const int b = blockIdx.x;

    uint64_t sb = (uint64_t)(logp_t + (size_t)b * TY_ * TX_);
    uint64_t db = (uint64_t)(diag_g + (size_t)b * (TY_ / 8) * 64);
    unsigned vo = (unsigned)(lane * 16);   // voffset into logp_t (bytes)
    unsigned df = (unsigned)(lane * 4);    // voffset into diag (bytes)

    float v0 = (lane == 0) ? 0.f : NEG_, v1 = NEG_, v2 = NEG_, v3 = NEG_;
    unsigned a0 = 0, a1 = 0, a2 = 0, a3 = 0;

    asm volatile(
        // ---- constants + 32-column prologue fill (cols 0..31) ----
        "v_mov_b32 v31, 0xce6e6b28\n\t"
        PRO("v[32:35]")   PRO("v[36:39]")   PRO("v[40:43]")   PRO("v[44:47]")
        PRO("v[48:51]")   PRO("v[52:55]")   PRO("v[56:59]")   PRO("v[60:63]")
        PRO("v[64:67]")   PRO("v[68:71]")   PRO("v[72:75]")   PRO("v[76:79]")
        PRO("v[80:83]")   PRO("v[84:87]")   PRO("v[88:91]")   PRO("v[92:95]")
        PRO("v[96:99]")   PRO("v[100:103]") PRO("v[104:107]") PRO("v[108:111]")
        PRO("v[112:115]") PRO("v[116:119]") PRO("v[120:123]") PRO("v[124:127]")
        PRO("v[128:131]") PRO("v[132:135]") PRO("v[136:139]") PRO("v[140:143]")
        PRO("v[144:147]") PRO("v[148:151]") PRO("v[152:155]") PRO("v[156:159]")
        "s_mov_b32 s26, 64\n\t"
        "Lmas_%=:\n\t"
        // ---- group 0: cols +0..7 (buffer v32..v63) ----
        WAITG
        COLA("v[32:35]", "v32", "v33", "v34", "v35")
        COLA("v[36:39]", "v36", "v37", "v38", "v39")
        COLA("v[40:43]", "v40", "v41", "v42", "v43")
        COLA("v[44:47]", "v44", "v45", "v46", "v47")
        COLA("v[48:51]", "v48", "v49", "v50", "v51")
        COLA("v[52:55]", "v52", "v53", "v54", "v55")
        COLA("v[56:59]", "v56", "v57", "v58", "v59")
        COLA("v[60:63]", "v60", "v61", "v62", "v63")
        STOREBLK
        // ---- group 1: cols +8..15 (v64..v95) ----
        WAITG
        COLA("v[64:67]", "v64", "v65", "v66", "v67")
        COLA("v[68:71]", "v68", "v69", "v70", "v71")
        COLA("v[72:75]", "v72", "v73", "v74", "v75")
        COLA("v[76:79]", "v76", "v77", "v78", "v79")
        COLA("v[80:83]", "v80", "v81", "v82", "v83")
        COLA("v[84:87]", "v84", "v85", "v86", "v87")
        COLA("v[88:91]", "v88", "v89", "v90", "v91")
        COLA("v[92:95]", "v92", "v93", "v94", "v95")
        STOREBLK
        // ---- group 2: cols +16..23 (v96..v127) ----
        WAITG
        COLA("v[96:99]",   "v96",  "v97",  "v98",  "v99")
        COLA("v[100:103]", "v100", "v101", "v102", "v103")
        COLA("v[104:107]", "v104", "v105", "v106", "v107")
        COLA("v[108:111]", "v108", "v109", "v110", "v111")
        COLA("v[112:115]", "v112", "v113", "v114", "v115")
        COLA("v[116:119]", "v116", "v117", "v118", "v119")
        COLA("v[120:123]", "v120", "v121", "v122", "v123")
        COLA("v[124:127]", "v124", "v125", "v126", "v127")
        STOREBLK
        // ---- group 3: cols +24..31 (v128..v159) ----
        WAITG
        COLA("v[128:131]", "v128", "v129", "v130", "v131")
        COLA("v[132:135]", "v132", "v133", "v134", "v135")
        COLA("v[136:139]", "v136", "v137", "v138", "v139")
        COLA("v[140:143]", "v140", "v141", "v142", "v143")
        COLA("v[144:147]", "v144", "v145", "v146", "v147")
        COLA("v[148:151]", "v148", "v149", "v150", "v151")
        COLA("v[152:155]", "v152", "v153", "v154", "v155")
        COLA("v[156:159]", "v156", "v157", "v158", "v159")
        STOREBLK
        "s_sub_u32 s26, s26, 1\n\t"
        "s_cmp_lg_u32 s26, 0\n\t"
        "s_cbranch_scc1 Lmas_%=\n\t"
        : [v0]"+v"(v0), [v1]"+v"(v1), [v2]"+v"(v2), [v3]"+v"(v3),
          [a0]"+v"(a0), [a1]"+v"(a1), [a2]"+v"(a2), [a3]"+v"(a3),
          [vo]"+v"(vo), [df]"+v"(df)
        : [sb]"s"(sb), [db]"s"(db)
        : "vcc", "scc", "memory",
          "s20","s21","s22","s23","s24","s25","s26",
          "v28","v29","v31",
          "v32","v33","v34","v35","v36","v37","v38","v39",
          "v40","v41","v42","v43","v44","v45","v46","v47",
          "v48","v49","v50","v51","v52","v53","v54","v55",
          "v56","v57","v58","v59","v60","v61","v62","v63",
          "v64","v65","v66","v67","v68","v69","v70","v71",
          "v72","v73","v74","v75","v76","v77","v78","v79",
          "v80","v81","v82","v83","v84","v85","v86","v87",
          "v88","v89","v90","v91","v92","v93","v94","v95",
          "v96","v97","v98","v99","v100","v101","v102","v103",
          "v104","v105","v106","v107","v108","v109","v110","v111",
          "v112","v113","v114","v115","v116","v117","v118","v119",
          "v120","v121","v122","v123","v124","v125","v126","v127",
          "v128","v129","v130","v131","v132","v133","v134","v135",
          "v136","v137","v138","v139","v140","v141","v142","v143",
          "v144","v145","v146","v147","v148","v149","v150","v151",
          "v152","v153","v154","v155","v156","v157","v158","v159");
    // NOTE: tail loads (cols 2048..2079) read past this batch's logp_t rows;
    // that memory is still inside d_out (attn/dr/logp slots) -> harmless.
}

// ---------------------------------------------------------------------------
// Kernel 2b: exit-table build. E_c[i] = row after walking chunk c (8 cols)
// entered at row i. grid (16 chunk-groups, 16 b) x 256 thr -> 256 blocks,
// 16 entries/thread, fully parallel across the whole GPU.
// ---------------------------------------------------------------------------
__global__ __launch_bounds__(256) void mas_tab_kernel(
    const unsigned int* __restrict__ diag_g, unsigned char* __restrict__ E_g)
{
    const int t  = threadIdx.x;        // entry row
    const int cg = blockIdx.x;         // chunk group of 16
    const int b  = blockIdx.y;
    const unsigned int* dg = diag_g + (size_t)b * (TY_ / 8) * 64;
    unsigned char* Eb = E_g + (size_t)b * (TY_ / 8) * 256;
    const int p = t >> 3;

    for (int k = 0; k < 16; ++k) {
        const int c = cg * 16 + k;
        unsigned long long W  = *(const unsigned long long*)&dg[c * 64 + 2 * p];
        unsigned long long Wl = p > 0
            ? *(const unsigned long long*)&dg[c * 64 + 2 * (p - 1)] : 0ULL;
        int ii = t;
#pragma unroll
        for (int jb = 7; jb >= 0; --jb) BT_STEP(jb)
        Eb[c * 256 + t] = (unsigned char)ii;
    }
}

// ---------------------------------------------------------------------------
// Kernel 2c: MAS backtrace via exit tables. Serial part is now only the
// 255-step chunk-entry chain (dependent LDS byte reads); emission of all
// 8-column chunks runs in parallel (1 thread/chunk). dr via LDS histogram.
// ---------------------------------------------------------------------------
__global__ __launch_bounds__(256) void mas_bt_kernel(
    const unsigned int* __restrict__ diag_g, const unsigned char* __restrict__ E_g,
    const int* __restrict__ xlen, const int* __restrict__ ylen,
    float* __restrict__ dr_out, int* __restrict__ idx_out)
{
    __shared__ unsigned char E[256 * 256];      // 64 KiB
    __shared__ unsigned char entry_s[256];
    __shared__ int rows_l[TY_];                 // 8 KiB
    __shared__ int cnt_l[TX_];                  // 1 KiB
    const int tid = threadIdx.x;
    const int b = blockIdx.x;
    const int x_len = xlen[b];
    const int y_len = ylen[b];

    cnt_l[tid] = 0;

    // copy E tables global->LDS, coalesced uint4
    const uint4* srcE = (const uint4*)(E_g + (size_t)b * (TY_ / 8) * 256);
    uint4* dstE = (uint4*)E;
#pragma unroll
    for (int it = 0; it < 16; ++it)
        dstE[tid + it * 256] = srcE[tid + it * 256];
    __syncthreads();

    const unsigned int* dg = diag_g + (size_t)b * (TY_ / 8) * 64;
    int* ib = idx_out + (size_t)b * TY_;
    const int jc = (y_len - 1) >> 3;

    if (tid == 0) {
        // partial top chunk (columns y_len-1 .. 8*jc), serial <=8 steps
        int ii = x_len - 1;
        int p = ii >> 3;
        unsigned long long W  = *(const unsigned long long*)&dg[jc * 64 + 2 * p];
        unsigned long long Wl = p > 0
            ? *(const unsigned long long*)&dg[jc * 64 + 2 * (p - 1)] : 0ULL;
        for (int jb = (y_len - 1) & 7; jb >= 0; --jb) {
            int j = 8 * jc + jb;
            ib[j] = ii; rows_l[j] = ii;
            BT_STEP(jb)
        }
        // entry chain over full chunks: 255 dependent LDS byte reads
        int cur = ii;
        for (int c = jc - 1; c >= 0; --c) {
            entry_s[c] = (unsigned char)cur;
            cur = E[c * 256 + cur];
        }
    }
    __syncthreads();

    // parallel emission: one thread per full chunk
    if (tid < jc) {
        const int c = tid;
        int ii = entry_s[c];
        int p = ii >> 3;
        unsigned long long W  = *(const unsigned long long*)&dg[c * 64 + 2 * p];
        unsigned long long Wl = p > 0
            ? *(const unsigned long long*)&dg[c * 64 + 2 * (p - 1)] : 0ULL;
        int r[8];
#pragma unroll
        for (int jb = 7; jb >= 0; --jb) {
            r[jb] = ii;
            BT_STEP(jb)
        }
        *reinterpret_cast<int4*>(&ib[8 * c])     = make_int4(r[0], r[1], r[2], r[3]);
        *reinterpret_cast<int4*>(&ib[8 * c + 4]) = make_int4(r[4], r[5], r[6], r[7]);
        *reinterpret_cast<int4*>(&rows_l[8 * c])     = make_int4(r[0], r[1], r[2], r[3]);
        *reinterpret_cast<int4*>(&rows_l[8 * c + 4]) = make_int4(r[4], r[5], r[6], r[7]);
    }
    __syncthreads();

    // dr[i] = #{ j < y_len : row(j) == i }
    for (int t = tid; t < TY_; t += 256)
        if (t < y_len) atomicAdd(&cnt_l[rows_l[t]], 1);
    __syncthreads();
    dr_out[(size_t)b * TX_ + tid] = (float)cnt_l[tid];
}

// ---------------------------------------------------------------------------
// Kernel 3: emit attn (one-hot path) and o_en_ex (gather of en rows).
// ---------------------------------------------------------------------------
__global__ __launch_bounds__(256) void emit_kernel(
    const float* __restrict__ en, const int* __restrict__ ylen,
    const int* __restrict__ idx_in, float* __restrict__ o_en,
    float* __restrict__ attn)
{
    const int tid = threadIdx.x;
    const int b = blockIdx.x;
    const int r = blockIdx.y;
    const int y_len = ylen[b];
    const int* ib = idx_in + (size_t)b * TY_;

    if (r < 256) {
        const int x = r;
        float* out = attn + ((size_t)b * TX_ + x) * TY_;
        for (int t = tid; t < TY_; t += 256) {
            int ii = ib[t];
            out[t] = (t < y_len && ii == x) ? 1.f : 0.f;
        }
    } else {
        const int h = r - 256;
        __shared__ float enr[256];
        enr[tid] = en[((size_t)b * H_ + h) * TX_ + tid];
        __syncthreads();
        float* out = o_en + ((size_t)b * H_ + h) * TY_;
        for (int t = tid; t < TY_; t += 256) {
            int ii = ib[t];
            bool a = (t < y_len);
            int is = a ? ii : 0;
            out[t] = a ? enr[is] : 0.f;
        }
    }
}

// ---------------------------------------------------------------------------
extern "C" void kernel_launch(void* const* d_in, const int* in_sizes, int n_in,
                              void* d_out, int out_size, void* d_ws, size_t ws_size,
                              hipStream_t stream)
{
    const float* en = (const float*)d_in[0];
    const float* mu = (const float*)d_in[1];
    const float* ls = (const float*)d_in[2];
    const float* y  = (const float*)d_in[3];
    const int* xl   = (const int*)d_in[4];
    const int* yl   = (const int*)d_in[5];

    float* o_en = (float*)d_out;                       // [16,256,2048]
    float* attn = o_en + (size_t)B_ * TX_ * TY_;       // [16,256,2048]
    float* dr   = attn + (size_t)B_ * TX_ * TY_;       // [16,256]
    float* logp = dr + (size_t)B_ * TX_;               // [16,256,2048]

    float* logp_t = attn;                              // scratch in attn slot
    // diag scratch in the o_en slot (1 MB; emit overwrites later)
    unsigned int* diag_g = (unsigned int*)o_en;
    // exit tables E in the logp_t region (dead after mas_fwd; 1 MB)
    unsigned char* E_g = (unsigned char*)logp_t;
    int* idxArr = (int*)d_ws;                          // [16,2048]

    dim3 g1(2, 16, 16);
    logp_kernel<<<g1, 256, 0, stream>>>(mu, ls, y, logp, logp_t);

    mas_fwd_kernel<<<dim3(16), dim3(64), 0, stream>>>(logp_t, diag_g);
    mas_tab_kernel<<<dim3(16, 16), dim3(256), 0, stream>>>(diag_g, E_g);
    mas_bt_kernel<<<dim3(16), dim3(256), 0, stream>>>(diag_g, E_g, xl, yl, dr, idxArr);

    dim3 g3(16, 512);
    emit_kernel<<<g3, 256, 0, stream>>>(en, yl, idxArr, o_en, attn);
}

// Round 4
// 290.751 us; speedup vs baseline: 1.0472x; 1.0091x over previous
//
#include <hip/hip_runtime.h>
#include <hip/hip_bf16.h>
#include <cstdint>
#include <cstddef>

#define B_ 16
#define TX_ 256
#define TY_ 2048
#define C_ 80
#define H_ 256
#define NEG_ -1e9f
#define NEG_I (int)0xCE6E6B28   // bit pattern of -1e9f

// one backtrace step at column-in-chunk jb from row ii, using window pair W
// (rows 8p..8p+7) with fallback Wl (rows 8p-8..8p-1).
// Diag bit layout (4 independent carry-push chains in fwd): within each
// 32-bit word (4 rows), row r = byte r; column jb at bit (7-jb). In the u64
// W, rows 8p..8p+3 are the low word, 8p+4..8p+7 the high word, so the bit
// for row ii, col jb sits at ((ii&7)<<3) | (7-jb).
#define BT_STEP(JB)                                                           \
    {                                                                         \
        unsigned bit = ((unsigned)(W >> (((ii & 7) << 3)                      \
                                         | (7 - (JB)))) & 1u)                 \
                     & (unsigned)(ii > 0);                                    \
        ii -= (int)bit;                                                       \
        W = (bit && ((ii & 7) == 7)) ? Wl : W;                                \
    }

// ---------------------------------------------------------------------------
// Kernel 1: logp[b,x,t] = -0.5*( S1 - 2*S2 + T3[x] )/C - 0.5*mean_c(ls[x])
// Register tile: 16 x * 4 t per thread. Also emits transposed logp_t [B,Ty,Tx]
// (into the attn slot of d_out) so MAS reads DP columns coalesced.
// ---------------------------------------------------------------------------
__global__ __launch_bounds__(256) void logp_kernel(
    const float* __restrict__ mu, const float* __restrict__ ls,
    const float* __restrict__ y, float* __restrict__ logp_out,
    float* __restrict__ logp_t)
{
    __shared__ float2 coef[16 * 80];
    __shared__ float  aux[16 * 80];
    __shared__ float  Kx[16];
    __shared__ float  yt[16 * 1028];

    const int tid = threadIdx.x;
    const int t0 = blockIdx.x * 1024;
    const int x0 = blockIdx.y * 16;
    const int b  = blockIdx.z;

    for (int i = tid; i < 16 * 80; i += 256) {
        int c = i >> 4, x = i & 15;
        float m = mu[(size_t)(b * C_ + c) * TX_ + x0 + x];
        float l = ls[(size_t)(b * C_ + c) * TX_ + x0 + x];
        float w = __expf(-2.f * l);
        coef[x * 80 + c] = make_float2(w, -2.f * m * w);
        aux[x * 80 + c]  = fmaf(m * m, w, l);
    }
    __syncthreads();
    if (tid < 16) {
        float s = 0.f;
        for (int c = 0; c < C_; ++c) s += aux[tid * 80 + c];
        Kx[tid] = -0.5f * s / (float)C_;
    }

    float acc[16][4];
#pragma unroll
    for (int x = 0; x < 16; ++x)
#pragma unroll
        for (int r = 0; r < 4; ++r) acc[x][r] = 0.f;

    const float4* y4 = (const float4*)y;
    for (int c0 = 0; c0 < C_; c0 += 16) {
        __syncthreads();
        for (int it = 0; it < 16; ++it) {
            int f = tid + it * 256;
            int t = f >> 2, k = f & 3;
            float4 v = y4[(size_t)(b * TY_ + t0 + t) * 20 + (c0 >> 2) + k];
            yt[(4 * k + 0) * 1028 + t] = v.x;
            yt[(4 * k + 1) * 1028 + t] = v.y;
            yt[(4 * k + 2) * 1028 + t] = v.z;
            yt[(4 * k + 3) * 1028 + t] = v.w;
        }
        __syncthreads();
        for (int cl = 0; cl < 16; ++cl) {
            const float4 yv = *reinterpret_cast<const float4*>(&yt[cl * 1028 + 4 * tid]);
            float4 y2 = make_float4(yv.x * yv.x, yv.y * yv.y, yv.z * yv.z, yv.w * yv.w);
#pragma unroll
            for (int x = 0; x < 16; ++x) {
                float2 f2 = coef[x * 80 + c0 + cl];
                acc[x][0] = fmaf(y2.x, f2.x, fmaf(yv.x, f2.y, acc[x][0]));
                acc[x][1] = fmaf(y2.y, f2.x, fmaf(yv.y, f2.y, acc[x][1]));
                acc[x][2] = fmaf(y2.z, f2.x, fmaf(yv.z, f2.y, acc[x][2]));
                acc[x][3] = fmaf(y2.w, f2.x, fmaf(yv.w, f2.y, acc[x][3]));
            }
        }
    }

#pragma unroll
    for (int x = 0; x < 16; ++x) {
        float kx = Kx[x];
#pragma unroll
        for (int r = 0; r < 4; ++r) acc[x][r] = fmaf(acc[x][r], -0.5f / (float)C_, kx);
        float4 out = make_float4(acc[x][0], acc[x][1], acc[x][2], acc[x][3]);
        *reinterpret_cast<float4*>(
            &logp_out[(size_t)(b * TX_ + x0 + x) * TY_ + t0 + 4 * tid]) = out;
    }
#pragma unroll
    for (int r = 0; r < 4; ++r) {
#pragma unroll
        for (int q = 0; q < 4; ++q) {
            float4 out = make_float4(acc[4 * q + 0][r], acc[4 * q + 1][r],
                                     acc[4 * q + 2][r], acc[4 * q + 3][r]);
            *reinterpret_cast<float4*>(
                &logp_t[(size_t)(b * TY_ + t0 + 4 * tid + r) * TX_ + x0 + 4 * q]) = out;
        }
    }
}

// ---------------------------------------------------------------------------
// Kernel 2a: MAS forward — FULL INLINE ASM scan, stall-free schedule.
// One wave per batch. 32-column prefetch buffer in v32..v159 (4 VGPR/col).
// Per column exactly 17 VALU + 1 VMEM, zero dependency stalls:
//   - sh is software-pipelined: column k's dpp (reading v3 AFTER its add,
//     2 slots later -> VALU->DPP hazard met) produces sh for column k+1,
//     ping-ponged v28<->v30. Lane0 of both stays NEG forever (DPP wave_shr
//     keep-old-dest on invalid lane, proven in R3).
//   - loads use offset: immediates; one v_add_u32 vo per 4 columns.
//   - counted s_waitcnt vmcnt(24) once per 8 columns (never 0).
// Diag word semantics identical to verified R2/R3 layout (consumers unchanged).
// ---------------------------------------------------------------------------
#define PROQ(A, Bq, Cq, Dq) \
    "global_load_dwordx4 " A ", %[vo], %[sb]\n\t" \
    "global_load_dwordx4 " Bq ", %[vo], %[sb] offset:0x400\n\t" \
    "global_load_dwordx4 " Cq ", %[vo], %[sb] offset:0x800\n\t" \
    "global_load_dwordx4 " Dq ", %[vo], %[sb] offset:0xC00\n\t" \
    "v_add_u32 %[vo], 0x1000, %[vo]\n\t"

#define ADDVO "v_add_u32 %[vo], 0x1000, %[vo]\n\t"

// SHU: sh register for THIS column; SHD: sh register produced for NEXT column.
#define COLN(RQ, R0, R1, R2, R3, SHU, SHD, OFF) \
    "v_cmp_gt_f32 vcc, " SHU ", %[v0]\n\t" \
    "v_cmp_gt_f32 s[20:21], %[v0], %[v1]\n\t" \
    "v_cmp_gt_f32 s[22:23], %[v1], %[v2]\n\t" \
    "v_cmp_gt_f32 s[24:25], %[v2], %[v3]\n\t" \
    "v_max_f32 %[v3], %[v2], %[v3]\n\t" \
    "v_max_f32 %[v2], %[v1], %[v2]\n\t" \
    "v_add_f32 %[v3], " R3 ", %[v3]\n\t" \
    "v_max_f32 %[v1], %[v0], %[v1]\n\t" \
    "v_max_f32 %[v0], " SHU ", %[v0]\n\t" \
    "v_mov_b32_dpp " SHD ", %[v3] wave_shr:1 row_mask:0xf bank_mask:0xf\n\t" \
    "v_add_f32 %[v2], " R2 ", %[v2]\n\t" \
    "v_add_f32 %[v1], " R1 ", %[v1]\n\t" \
    "v_add_f32 %[v0], " R0 ", %[v0]\n\t" \
    "v_addc_co_u32 %[a0], vcc, %[a0], %[a0], vcc\n\t" \
    "v_addc_co_u32 %[a1], s[20:21], %[a1], %[a1], s[20:21]\n\t" \
    "v_addc_co_u32 %[a2], s[22:23], %[a2], %[a2], s[22:23]\n\t" \
    "v_addc_co_u32 %[a3], s[24:25], %[a3], %[a3], s[24:25]\n\t" \
    "global_load_dwordx4 " RQ ", %[vo], %[sb] offset:" OFF "\n\t"

#define STOREBLK(OFFD) \
    "v_lshl_or_b32 v29, %[a1], 8, %[a0]\n\t" \
    "v_lshl_or_b32 v29, %[a2], 16, v29\n\t" \
    "v_lshl_or_b32 v29, %[a3], 24, v29\n\t" \
    "global_store_dword %[df], v29, %[db] offset:" OFFD "\n\t" \
    "v_mov_b32 %[a0], 0\n\t" \
    "v_mov_b32 %[a1], 0\n\t" \
    "v_mov_b32 %[a2], 0\n\t" \
    "v_mov_b32 %[a3], 0\n\t"

#define WAITG "s_waitcnt vmcnt(24)\n\t"

__global__ __launch_bounds__(64, 1) void mas_fwd_kernel(
    const float* __restrict__ logp_t, unsigned int* __restrict__ diag_g)
{
    const int lane = threadIdx.x;
    const int b = blockIdx.x;

    uint64_t sb = (uint64_t)(logp_t + (size_t)b * TY_ * TX_);
    uint64_t db = (uint64_t)(diag_g + (size_t)b * (TY_ / 8) * 64);
    unsigned vo = (unsigned)(lane * 16);   // voffset into logp_t (bytes)
    unsigned df = (unsigned)(lane * 4);    // voffset into diag (bytes)

    float v0 = (lane == 0) ? 0.f : NEG_, v1 = NEG_, v2 = NEG_, v3 = NEG_;
    unsigned a0 = 0, a1 = 0, a2 = 0, a3 = 0;

    asm volatile(
        // ---- sh ping-pong init (all lanes NEG; lane0 persists NEG) ----
        "v_mov_b32 v28, 0xce6e6b28\n\t"
        "v_mov_b32 v30, 0xce6e6b28\n\t"
        // ---- 32-column prologue fill (cols 0..31) ----
        PROQ("v[32:35]",   "v[36:39]",   "v[40:43]",   "v[44:47]")
        PROQ("v[48:51]",   "v[52:55]",   "v[56:59]",   "v[60:63]")
        PROQ("v[64:67]",   "v[68:71]",   "v[72:75]",   "v[76:79]")
        PROQ("v[80:83]",   "v[84:87]",   "v[88:91]",   "v[92:95]")
        PROQ("v[96:99]",   "v[100:103]", "v[104:107]", "v[108:111]")
        PROQ("v[112:115]", "v[116:119]", "v[120:123]", "v[124:127]")
        PROQ("v[128:131]", "v[132:135]", "v[136:139]", "v[140:143]")
        PROQ("v[144:147]", "v[148:151]", "v[152:155]", "v[156:159]")
        "s_mov_b32 s26, 64\n\t"
        "Lmas_%=:\n\t"
        // ---- group 0: cols +0..7 (buffer v32..v63) ----
        WAITG
        COLN("v[32:35]", "v32", "v33", "v34", "v35", "v28", "v30", "0")
        COLN("v[36:39]", "v36", "v37", "v38", "v39", "v30", "v28", "0x400")
        COLN("v[40:43]", "v40", "v41", "v42", "v43", "v28", "v30", "0x800")
        COLN("v[44:47]", "v44", "v45", "v46", "v47", "v30", "v28", "0xC00")
        ADDVO
        COLN("v[48:51]", "v48", "v49", "v50", "v51", "v28", "v30", "0")
        COLN("v[52:55]", "v52", "v53", "v54", "v55", "v30", "v28", "0x400")
        COLN("v[56:59]", "v56", "v57", "v58", "v59", "v28", "v30", "0x800")
        COLN("v[60:63]", "v60", "v61", "v62", "v63", "v30", "v28", "0xC00")
        ADDVO
        STOREBLK("0")
        // ---- group 1: cols +8..15 (v64..v95) ----
        WAITG
        COLN("v[64:67]", "v64", "v65", "v66", "v67", "v28", "v30", "0")
        COLN("v[68:71]", "v68", "v69", "v70", "v71", "v30", "v28", "0x400")
        COLN("v[72:75]", "v72", "v73", "v74", "v75", "v28", "v30", "0x800")
        COLN("v[76:79]", "v76", "v77", "v78", "v79", "v30", "v28", "0xC00")
        ADDVO
        COLN("v[80:83]", "v80", "v81", "v82", "v83", "v28", "v30", "0")
        COLN("v[84:87]", "v84", "v85", "v86", "v87", "v30", "v28", "0x400")
        COLN("v[88:91]", "v88", "v89", "v90", "v91", "v28", "v30", "0x800")
        COLN("v[92:95]", "v92", "v93", "v94", "v95", "v30", "v28", "0xC00")
        ADDVO
        STOREBLK("0x100")
        // ---- group 2: cols +16..23 (v96..v127) ----
        WAITG
        COLN("v[96:99]",   "v96",  "v97",  "v98",  "v99",  "v28", "v30", "0")
        COLN("v[100:103]", "v100", "v101", "v102", "v103", "v30", "v28", "0x400")
        COLN("v[104:107]", "v104", "v105", "v106", "v107", "v28", "v30", "0x800")
        COLN("v[108:111]", "v108", "v109", "v110", "v111", "v30", "v28", "0xC00")
        ADDVO
        COLN("v[112:115]", "v112", "v113", "v114", "v115", "v28", "v30", "0")
        COLN("v[116:119]", "v116", "v117", "v118", "v119", "v30", "v28", "0x400")
        COLN("v[120:123]", "v120", "v121", "v122", "v123", "v28", "v30", "0x800")
        COLN("v[124:127]", "v124", "v125", "v126", "v127", "v30", "v28", "0xC00")
        ADDVO
        STOREBLK("0x200")
        // ---- group 3: cols +24..31 (v128..v159) ----
        WAITG
        COLN("v[128:131]", "v128", "v129", "v130", "v131", "v28", "v30", "0")
        COLN("v[132:135]", "v132", "v133", "v134", "v135", "v30", "v28", "0x400")
        COLN("v[136:139]", "v136", "v137", "v138", "v139", "v28", "v30", "0x800")
        COLN("v[140:143]", "v140", "v141", "v142", "v143", "v30", "v28", "0xC00")
        ADDVO
        COLN("v[144:147]", "v144", "v145", "v146", "v147", "v28", "v30", "0")
        COLN("v[148:151]", "v148", "v149", "v150", "v151", "v30", "v28", "0x400")
        COLN("v[152:155]", "v152", "v153", "v154", "v155", "v28", "v30", "0x800")
        COLN("v[156:159]", "v156", "v157", "v158", "v159", "v30", "v28", "0xC00")
        ADDVO
        STOREBLK("0x300")
        "v_add_u32 %[df], 0x400, %[df]\n\t"
        "s_sub_u32 s26, s26, 1\n\t"
        "s_cmp_lg_u32 s26, 0\n\t"
        "s_cbranch_scc1 Lmas_%=\n\t"
        : [v0]"+v"(v0), [v1]"+v"(v1), [v2]"+v"(v2), [v3]"+v"(v3),
          [a0]"+v"(a0), [a1]"+v"(a1), [a2]"+v"(a2), [a3]"+v"(a3),
          [vo]"+v"(vo), [df]"+v"(df)
        : [sb]"s"(sb), [db]"s"(db)
        : "vcc", "scc", "memory",
          "s20","s21","s22","s23","s24","s25","s26",
          "v28","v29","v30",
          "v32","v33","v34","v35","v36","v37","v38","v39",
          "v40","v41","v42","v43","v44","v45","v46","v47",
          "v48","v49","v50","v51","v52","v53","v54","v55",
          "v56","v57","v58","v59","v60","v61","v62","v63",
          "v64","v65","v66","v67","v68","v69","v70","v71",
          "v72","v73","v74","v75","v76","v77","v78","v79",
          "v80","v81","v82","v83","v84","v85","v86","v87",
          "v88","v89","v90","v91","v92","v93","v94","v95",
          "v96","v97","v98","v99","v100","v101","v102","v103",
          "v104","v105","v106","v107","v108","v109","v110","v111",
          "v112","v113","v114","v115","v116","v117","v118","v119",
          "v120","v121","v122","v123","v124","v125","v126","v127",
          "v128","v129","v130","v131","v132","v133","v134","v135",
          "v136","v137","v138","v139","v140","v141","v142","v143",
          "v144","v145","v146","v147","v148","v149","v150","v151",
          "v152","v153","v154","v155","v156","v157","v158","v159");
    // NOTE: tail loads (cols 2048..2079) read past this batch's logp_t rows;
    // that memory is still inside d_out (attn/dr/logp slots) -> harmless.
}

// ---------------------------------------------------------------------------
// Kernel 2b: exit-table build. E_c[i] = row after walking chunk c (8 cols)
// entered at row i. grid (16 chunk-groups, 16 b) x 256 thr -> 256 blocks,
// 16 entries/thread, fully parallel across the whole GPU.
// ---------------------------------------------------------------------------
__global__ __launch_bounds__(256) void mas_tab_kernel(
    const unsigned int* __restrict__ diag_g, unsigned char* __restrict__ E_g)
{
    const int t  = threadIdx.x;        // entry row
    const int cg = blockIdx.x;         // chunk group of 16
    const int b  = blockIdx.y;
    const unsigned int* dg = diag_g + (size_t)b * (TY_ / 8) * 64;
    unsigned char* Eb = E_g + (size_t)b * (TY_ / 8) * 256;
    const int p = t >> 3;

    for (int k = 0; k < 16; ++k) {
        const int c = cg * 16 + k;
        unsigned long long W  = *(const unsigned long long*)&dg[c * 64 + 2 * p];
        unsigned long long Wl = p > 0
            ? *(const unsigned long long*)&dg[c * 64 + 2 * (p - 1)] : 0ULL;
        int ii = t;
#pragma unroll
        for (int jb = 7; jb >= 0; --jb) BT_STEP(jb)
        Eb[c * 256 + t] = (unsigned char)ii;
    }
}

// ---------------------------------------------------------------------------
// Kernel 2c: MAS backtrace via exit tables. Serial part is now only the
// 255-step chunk-entry chain (dependent LDS byte reads); emission of all
// 8-column chunks runs in parallel (1 thread/chunk). dr via LDS histogram.
// ---------------------------------------------------------------------------
__global__ __launch_bounds__(256) void mas_bt_kernel(
    const unsigned int* __restrict__ diag_g, const unsigned char* __restrict__ E_g,
    const int* __restrict__ xlen, const int* __restrict__ ylen,
    float* __restrict__ dr_out, int* __restrict__ idx_out)
{
    __shared__ unsigned char E[256 * 256];      // 64 KiB
    __shared__ unsigned char entry_s[256];
    __shared__ int rows_l[TY_];                 // 8 KiB
    __shared__ int cnt_l[TX_];                  // 1 KiB
    const int tid = threadIdx.x;
    const int b = blockIdx.x;
    const int x_len = xlen[b];
    const int y_len = ylen[b];

    cnt_l[tid] = 0;

    // copy E tables global->LDS, coalesced uint4
    const uint4* srcE = (const uint4*)(E_g + (size_t)b * (TY_ / 8) * 256);
    uint4* dstE = (uint4*)E;
#pragma unroll
    for (int it = 0; it < 16; ++it)
        dstE[tid + it * 256] = srcE[tid + it * 256];
    __syncthreads();

    const unsigned int* dg = diag_g + (size_t)b * (TY_ / 8) * 64;
    int* ib = idx_out + (size_t)b * TY_;
    const int jc = (y_len - 1) >> 3;

    if (tid == 0) {
        // partial top chunk (columns y_len-1 .. 8*jc), serial <=8 steps
        int ii = x_len - 1;
        int p = ii >> 3;
        unsigned long long W  = *(const unsigned long long*)&dg[jc * 64 + 2 * p];
        unsigned long long Wl = p > 0
            ? *(const unsigned long long*)&dg[jc * 64 + 2 * (p - 1)] : 0ULL;
        for (int jb = (y_len - 1) & 7; jb >= 0; --jb) {
            int j = 8 * jc + jb;
            ib[j] = ii; rows_l[j] = ii;
            BT_STEP(jb)
        }
        // entry chain over full chunks: 255 dependent LDS byte reads
        int cur = ii;
        for (int c = jc - 1; c >= 0; --c) {
            entry_s[c] = (unsigned char)cur;
            cur = E[c * 256 + cur];
        }
    }
    __syncthreads();

    // parallel emission: one thread per full chunk
    if (tid < jc) {
        const int c = tid;
        int ii = entry_s[c];
        int p = ii >> 3;
        unsigned long long W  = *(const unsigned long long*)&dg[c * 64 + 2 * p];
        unsigned long long Wl = p > 0
            ? *(const unsigned long long*)&dg[c * 64 + 2 * (p - 1)] : 0ULL;
        int r[8];
#pragma unroll
        for (int jb = 7; jb >= 0; --jb) {
            r[jb] = ii;
            BT_STEP(jb)
        }
        *reinterpret_cast<int4*>(&ib[8 * c])     = make_int4(r[0], r[1], r[2], r[3]);
        *reinterpret_cast<int4*>(&ib[8 * c + 4]) = make_int4(r[4], r[5], r[6], r[7]);
        *reinterpret_cast<int4*>(&rows_l[8 * c])     = make_int4(r[0], r[1], r[2], r[3]);
        *reinterpret_cast<int4*>(&rows_l[8 * c + 4]) = make_int4(r[4], r[5], r[6], r[7]);
    }
    __syncthreads();

    // dr[i] = #{ j < y_len : row(j) == i }
    for (int t = tid; t < TY_; t += 256)
        if (t < y_len) atomicAdd(&cnt_l[rows_l[t]], 1);
    __syncthreads();
    dr_out[(size_t)b * TX_ + tid] = (float)cnt_l[tid];
}

// ---------------------------------------------------------------------------
// Kernel 3: emit attn (one-hot path) and o_en_ex (gather of en rows).
// ---------------------------------------------------------------------------
__global__ __launch_bounds__(256) void emit_kernel(
    const float* __restrict__ en, const int* __restrict__ ylen,
    const int* __restrict__ idx_in, float* __restrict__ o_en,
    float* __restrict__ attn)
{
    const int tid = threadIdx.x;
    const int b = blockIdx.x;
    const int r = blockIdx.y;
    const int y_len = ylen[b];
    const int* ib = idx_in + (size_t)b * TY_;

    if (r < 256) {
        const int x = r;
        float* out = attn + ((size_t)b * TX_ + x) * TY_;
        for (int t = tid; t < TY_; t += 256) {
            int ii = ib[t];
            out[t] = (t < y_len && ii == x) ? 1.f : 0.f;
        }
    } else {
        const int h = r - 256;
        __shared__ float enr[256];
        enr[tid] = en[((size_t)b * H_ + h) * TX_ + tid];
        __syncthreads();
        float* out = o_en + ((size_t)b * H_ + h) * TY_;
        for (int t = tid; t < TY_; t += 256) {
            int ii = ib[t];
            bool a = (t < y_len);
            int is = a ? ii : 0;
            out[t] = a ? enr[is] : 0.f;
        }
    }
}

// ---------------------------------------------------------------------------
extern "C" void kernel_launch(void* const* d_in, const int* in_sizes, int n_in,
                              void* d_out, int out_size, void* d_ws, size_t ws_size,
                              hipStream_t stream)
{
    const float* en = (const float*)d_in[0];
    const float* mu = (const float*)d_in[1];
    const float* ls = (const float*)d_in[2];
    const float* y  = (const float*)d_in[3];
    const int* xl   = (const int*)d_in[4];
    const int* yl   = (const int*)d_in[5];

    float* o_en = (float*)d_out;                       // [16,256,2048]
    float* attn = o_en + (size_t)B_ * TX_ * TY_;       // [16,256,2048]
    float* dr   = attn + (size_t)B_ * TX_ * TY_;       // [16,256]
    float* logp = dr + (size_t)B_ * TX_;               // [16,256,2048]

    float* logp_t = attn;                              // scratch in attn slot
    // diag scratch in the o_en slot (1 MB; emit overwrites later)
    unsigned int* diag_g = (unsigned int*)o_en;
    // exit tables E in the logp_t region (dead after mas_fwd; 1 MB)
    unsigned char* E_g = (unsigned char*)logp_t;
    int* idxArr = (int*)d_ws;                          // [16,2048]

    dim3 g1(2, 16, 16);
    logp_kernel<<<g1, 256, 0, stream>>>(mu, ls, y, logp, logp_t);

    mas_fwd_kernel<<<dim3(16), dim3(64), 0, stream>>>(logp_t, diag_g);
    mas_tab_kernel<<<dim3(16, 16), dim3(256), 0, stream>>>(diag_g, E_g);
    mas_bt_kernel<<<dim3(16), dim3(256), 0, stream>>>(diag_g, E_g, xl, yl, dr, idxArr);

    dim3 g3(16, 512);
    emit_kernel<<<g3, 256, 0, stream>>>(en, yl, idxArr, o_en, attn);
}

// Round 8
// 282.351 us; speedup vs baseline: 1.0784x; 1.0298x over previous
//
#include <hip/hip_runtime.h>
#include <hip/hip_bf16.h>
#include <cstdint>
#include <cstddef>

#define B_ 16
#define TX_ 256
#define TY_ 2048
#define C_ 80
#define H_ 256
#define NEG_ -1e9f
#define NEG_I (int)0xCE6E6B28   // bit pattern of -1e9f

// one backtrace step at column-in-chunk jb from row ii, using window pair W
// (rows 8p..8p+7) with fallback Wl (rows 8p-8..8p-1).
// Diag bit layout (4 independent carry-push chains in fwd): within each
// 32-bit word (4 rows), row r = byte r; column jb at bit (7-jb). In the u64
// W, rows 8p..8p+3 are the low word, 8p+4..8p+7 the high word, so the bit
// for row ii, col jb sits at ((ii&7)<<3) | (7-jb).
#define BT_STEP(JB)                                                           \
    {                                                                         \
        unsigned bit = ((unsigned)(W >> (((ii & 7) << 3)                      \
                                         | (7 - (JB)))) & 1u)                 \
                     & (unsigned)(ii > 0);                                    \
        ii -= (int)bit;                                                       \
        W = (bit && ((ii & 7) == 7)) ? Wl : W;                                \
    }

// ---------------------------------------------------------------------------
// Kernel 1: logp (unchanged, verified).
// ---------------------------------------------------------------------------
__global__ __launch_bounds__(256) void logp_kernel(
    const float* __restrict__ mu, const float* __restrict__ ls,
    const float* __restrict__ y, float* __restrict__ logp_out,
    float* __restrict__ logp_t)
{
    __shared__ float2 coef[16 * 80];
    __shared__ float  aux[16 * 80];
    __shared__ float  Kx[16];
    __shared__ float  yt[16 * 1028];

    const int tid = threadIdx.x;
    const int t0 = blockIdx.x * 1024;
    const int x0 = blockIdx.y * 16;
    const int b  = blockIdx.z;

    for (int i = tid; i < 16 * 80; i += 256) {
        int c = i >> 4, x = i & 15;
        float m = mu[(size_t)(b * C_ + c) * TX_ + x0 + x];
        float l = ls[(size_t)(b * C_ + c) * TX_ + x0 + x];
        float w = __expf(-2.f * l);
        coef[x * 80 + c] = make_float2(w, -2.f * m * w);
        aux[x * 80 + c]  = fmaf(m * m, w, l);
    }
    __syncthreads();
    if (tid < 16) {
        float s = 0.f;
        for (int c = 0; c < C_; ++c) s += aux[tid * 80 + c];
        Kx[tid] = -0.5f * s / (float)C_;
    }

    float acc[16][4];
#pragma unroll
    for (int x = 0; x < 16; ++x)
#pragma unroll
        for (int r = 0; r < 4; ++r) acc[x][r] = 0.f;

    const float4* y4 = (const float4*)y;
    for (int c0 = 0; c0 < C_; c0 += 16) {
        __syncthreads();
        for (int it = 0; it < 16; ++it) {
            int f = tid + it * 256;
            int t = f >> 2, k = f & 3;
            float4 v = y4[(size_t)(b * TY_ + t0 + t) * 20 + (c0 >> 2) + k];
            yt[(4 * k + 0) * 1028 + t] = v.x;
            yt[(4 * k + 1) * 1028 + t] = v.y;
            yt[(4 * k + 2) * 1028 + t] = v.z;
            yt[(4 * k + 3) * 1028 + t] = v.w;
        }
        __syncthreads();
        for (int cl = 0; cl < 16; ++cl) {
            const float4 yv = *reinterpret_cast<const float4*>(&yt[cl * 1028 + 4 * tid]);
            float4 y2 = make_float4(yv.x * yv.x, yv.y * yv.y, yv.z * yv.z, yv.w * yv.w);
#pragma unroll
            for (int x = 0; x < 16; ++x) {
                float2 f2 = coef[x * 80 + c0 + cl];
                acc[x][0] = fmaf(y2.x, f2.x, fmaf(yv.x, f2.y, acc[x][0]));
                acc[x][1] = fmaf(y2.y, f2.x, fmaf(yv.y, f2.y, acc[x][1]));
                acc[x][2] = fmaf(y2.z, f2.x, fmaf(yv.z, f2.y, acc[x][2]));
                acc[x][3] = fmaf(y2.w, f2.x, fmaf(yv.w, f2.y, acc[x][3]));
            }
        }
    }

#pragma unroll
    for (int x = 0; x < 16; ++x) {
        float kx = Kx[x];
#pragma unroll
        for (int r = 0; r < 4; ++r) acc[x][r] = fmaf(acc[x][r], -0.5f / (float)C_, kx);
        float4 out = make_float4(acc[x][0], acc[x][1], acc[x][2], acc[x][3]);
        *reinterpret_cast<float4*>(
            &logp_out[(size_t)(b * TX_ + x0 + x) * TY_ + t0 + 4 * tid]) = out;
    }
#pragma unroll
    for (int r = 0; r < 4; ++r) {
#pragma unroll
        for (int q = 0; q < 4; ++q) {
            float4 out = make_float4(acc[4 * q + 0][r], acc[4 * q + 1][r],
                                     acc[4 * q + 2][r], acc[4 * q + 3][r]);
            *reinterpret_cast<float4*>(
                &logp_t[(size_t)(b * TY_ + t0 + 4 * tid + r) * TX_ + x0 + 4 * q]) = out;
        }
    }
}

// ---------------------------------------------------------------------------
// Kernel 2a: MAS forward — R4-VERIFIED full inline asm scan (single wave per
// batch, stall-free schedule, 32-col prefetch in v32..v159, vmcnt(24)).
// ---------------------------------------------------------------------------
#define PROQ(A, Bq, Cq, Dq) \
    "global_load_dwordx4 " A ", %[vo], %[sb]\n\t" \
    "global_load_dwordx4 " Bq ", %[vo], %[sb] offset:0x400\n\t" \
    "global_load_dwordx4 " Cq ", %[vo], %[sb] offset:0x800\n\t" \
    "global_load_dwordx4 " Dq ", %[vo], %[sb] offset:0xC00\n\t" \
    "v_add_u32 %[vo], 0x1000, %[vo]\n\t"

#define ADDVO "v_add_u32 %[vo], 0x1000, %[vo]\n\t"

// SHU: sh register for THIS column; SHD: sh register produced for NEXT column.
#define COLN(RQ, R0, R1, R2, R3, SHU, SHD, OFF) \
    "v_cmp_gt_f32 vcc, " SHU ", %[v0]\n\t" \
    "v_cmp_gt_f32 s[20:21], %[v0], %[v1]\n\t" \
    "v_cmp_gt_f32 s[22:23], %[v1], %[v2]\n\t" \
    "v_cmp_gt_f32 s[24:25], %[v2], %[v3]\n\t" \
    "v_max_f32 %[v3], %[v2], %[v3]\n\t" \
    "v_max_f32 %[v2], %[v1], %[v2]\n\t" \
    "v_add_f32 %[v3], " R3 ", %[v3]\n\t" \
    "v_max_f32 %[v1], %[v0], %[v1]\n\t" \
    "v_max_f32 %[v0], " SHU ", %[v0]\n\t" \
    "v_mov_b32_dpp " SHD ", %[v3] wave_shr:1 row_mask:0xf bank_mask:0xf\n\t" \
    "v_add_f32 %[v2], " R2 ", %[v2]\n\t" \
    "v_add_f32 %[v1], " R1 ", %[v1]\n\t" \
    "v_add_f32 %[v0], " R0 ", %[v0]\n\t" \
    "v_addc_co_u32 %[a0], vcc, %[a0], %[a0], vcc\n\t" \
    "v_addc_co_u32 %[a1], s[20:21], %[a1], %[a1], s[20:21]\n\t" \
    "v_addc_co_u32 %[a2], s[22:23], %[a2], %[a2], s[22:23]\n\t" \
    "v_addc_co_u32 %[a3], s[24:25], %[a3], %[a3], s[24:25]\n\t" \
    "global_load_dwordx4 " RQ ", %[vo], %[sb] offset:" OFF "\n\t"

#define STOREBLK(OFFD) \
    "v_lshl_or_b32 v29, %[a1], 8, %[a0]\n\t" \
    "v_lshl_or_b32 v29, %[a2], 16, v29\n\t" \
    "v_lshl_or_b32 v29, %[a3], 24, v29\n\t" \
    "global_store_dword %[df], v29, %[db] offset:" OFFD "\n\t" \
    "v_mov_b32 %[a0], 0\n\t" \
    "v_mov_b32 %[a1], 0\n\t" \
    "v_mov_b32 %[a2], 0\n\t" \
    "v_mov_b32 %[a3], 0\n\t"

#define WAITG "s_waitcnt vmcnt(24)\n\t"

__global__ __launch_bounds__(64, 1) void mas_fwd_kernel(
    const float* __restrict__ logp_t, unsigned int* __restrict__ diag_g)
{
    const int lane = threadIdx.x;
    const int b = blockIdx.x;

    uint64_t sb = (uint64_t)(logp_t + (size_t)b * TY_ * TX_);
    uint64_t db = (uint64_t)(diag_g + (size_t)b * (TY_ / 8) * 64);
    unsigned vo = (unsigned)(lane * 16);   // voffset into logp_t (bytes)
    unsigned df = (unsigned)(lane * 4);    // voffset into diag (bytes)

    float v0 = (lane == 0) ? 0.f : NEG_, v1 = NEG_, v2 = NEG_, v3 = NEG_;
    unsigned a0 = 0, a1 = 0, a2 = 0, a3 = 0;

    asm volatile(
        // ---- sh ping-pong init (all lanes NEG; lane0 persists NEG) ----
        "v_mov_b32 v28, 0xce6e6b28\n\t"
        "v_mov_b32 v30, 0xce6e6b28\n\t"
        // ---- 32-column prologue fill (cols 0..31) ----
        PROQ("v[32:35]",   "v[36:39]",   "v[40:43]",   "v[44:47]")
        PROQ("v[48:51]",   "v[52:55]",   "v[56:59]",   "v[60:63]")
        PROQ("v[64:67]",   "v[68:71]",   "v[72:75]",   "v[76:79]")
        PROQ("v[80:83]",   "v[84:87]",   "v[88:91]",   "v[92:95]")
        PROQ("v[96:99]",   "v[100:103]", "v[104:107]", "v[108:111]")
        PROQ("v[112:115]", "v[116:119]", "v[120:123]", "v[124:127]")
        PROQ("v[128:131]", "v[132:135]", "v[136:139]", "v[140:143]")
        PROQ("v[144:147]", "v[148:151]", "v[152:155]", "v[156:159]")
        "s_mov_b32 s26, 64\n\t"
        "Lmas_%=:\n\t"
        // ---- group 0: cols +0..7 (buffer v32..v63) ----
        WAITG
        COLN("v[32:35]", "v32", "v33", "v34", "v35", "v28", "v30", "0")
        COLN("v[36:39]", "v36", "v37", "v38", "v39", "v30", "v28", "0x400")
        COLN("v[40:43]", "v40", "v41", "v42", "v43", "v28", "v30", "0x800")
        COLN("v[44:47]", "v44", "v45", "v46", "v47", "v30", "v28", "0xC00")
        ADDVO
        COLN("v[48:51]", "v48", "v49", "v50", "v51", "v28", "v30", "0")
        COLN("v[52:55]", "v52", "v53", "v54", "v55", "v30", "v28", "0x400")
        COLN("v[56:59]", "v56", "v57", "v58", "v59", "v28", "v30", "0x800")
        COLN("v[60:63]", "v60", "v61", "v62", "v63", "v30", "v28", "0xC00")
        ADDVO
        STOREBLK("0")
        // ---- group 1: cols +8..15 (v64..v95) ----
        WAITG
        COLN("v[64:67]", "v64", "v65", "v66", "v67", "v28", "v30", "0")
        COLN("v[68:71]", "v68", "v69", "v70", "v71", "v30", "v28", "0x400")
        COLN("v[72:75]", "v72", "v73", "v74", "v75", "v28", "v30", "0x800")
        COLN("v[76:79]", "v76", "v77", "v78", "v79", "v30", "v28", "0xC00")
        ADDVO
        COLN("v[80:83]", "v80", "v81", "v82", "v83", "v28", "v30", "0")
        COLN("v[84:87]", "v84", "v85", "v86", "v87", "v30", "v28", "0x400")
        COLN("v[88:91]", "v88", "v89", "v90", "v91", "v28", "v30", "0x800")
        COLN("v[92:95]", "v92", "v93", "v94", "v95", "v30", "v28", "0xC00")
        ADDVO
        STOREBLK("0x100")
        // ---- group 2: cols +16..23 (v96..v127) ----
        WAITG
        COLN("v[96:99]",   "v96",  "v97",  "v98",  "v99",  "v28", "v30", "0")
        COLN("v[100:103]", "v100", "v101", "v102", "v103", "v30", "v28", "0x400")
        COLN("v[104:107]", "v104", "v105", "v106", "v107", "v28", "v30", "0x800")
        COLN("v[108:111]", "v108", "v109", "v110", "v111", "v30", "v28", "0xC00")
        ADDVO
        COLN("v[112:115]", "v112", "v113", "v114", "v115", "v28", "v30", "0")
        COLN("v[116:119]", "v116", "v117", "v118", "v119", "v30", "v28", "0x400")
        COLN("v[120:123]", "v120", "v121", "v122", "v123", "v28", "v30", "0x800")
        COLN("v[124:127]", "v124", "v125", "v126", "v127", "v30", "v28", "0xC00")
        ADDVO
        STOREBLK("0x200")
        // ---- group 3: cols +24..31 (v128..v159) ----
        WAITG
        COLN("v[128:131]", "v128", "v129", "v130", "v131", "v28", "v30", "0")
        COLN("v[132:135]", "v132", "v133", "v134", "v135", "v30", "v28", "0x400")
        COLN("v[136:139]", "v136", "v137", "v138", "v139", "v28", "v30", "0x800")
        COLN("v[140:143]", "v140", "v141", "v142", "v143", "v30", "v28", "0xC00")
        ADDVO
        COLN("v[144:147]", "v144", "v145", "v146", "v147", "v28", "v30", "0")
        COLN("v[148:151]", "v148", "v149", "v150", "v151", "v30", "v28", "0x400")
        COLN("v[152:155]", "v152", "v153", "v154", "v155", "v28", "v30", "0x800")
        COLN("v[156:159]", "v156", "v157", "v158", "v159", "v30", "v28", "0xC00")
        ADDVO
        STOREBLK("0x300")
        "v_add_u32 %[df], 0x400, %[df]\n\t"
        "s_sub_u32 s26, s26, 1\n\t"
        "s_cmp_lg_u32 s26, 0\n\t"
        "s_cbranch_scc1 Lmas_%=\n\t"
        : [v0]"+v"(v0), [v1]"+v"(v1), [v2]"+v"(v2), [v3]"+v"(v3),
          [a0]"+v"(a0), [a1]"+v"(a1), [a2]"+v"(a2), [a3]"+v"(a3),
          [vo]"+v"(vo), [df]"+v"(df)
        : [sb]"s"(sb), [db]"s"(db)
        : "vcc", "scc", "memory",
          "s20","s21","s22","s23","s24","s25","s26",
          "v28","v29","v30",
          "v32","v33","v34","v35","v36","v37","v38","v39",
          "v40","v41","v42","v43","v44","v45","v46","v47",
          "v48","v49","v50","v51","v52","v53","v54","v55",
          "v56","v57","v58","v59","v60","v61","v62","v63",
          "v64","v65","v66","v67","v68","v69","v70","v71",
          "v72","v73","v74","v75","v76","v77","v78","v79",
          "v80","v81","v82","v83","v84","v85","v86","v87",
          "v88","v89","v90","v91","v92","v93","v94","v95",
          "v96","v97","v98","v99","v100","v101","v102","v103",
          "v104","v105","v106","v107","v108","v109","v110","v111",
          "v112","v113","v114","v115","v116","v117","v118","v119",
          "v120","v121","v122","v123","v124","v125","v126","v127",
          "v128","v129","v130","v131","v132","v133","v134","v135",
          "v136","v137","v138","v139","v140","v141","v142","v143",
          "v144","v145","v146","v147","v148","v149","v150","v151",
          "v152","v153","v154","v155","v156","v157","v158","v159");
    // NOTE: tail loads (cols 2048..2079) read past this batch's logp_t rows;
    // that memory is still inside the surrounding buffer -> harmless.
}

// ---------------------------------------------------------------------------
// Kernel 2b: exit-table build (unchanged).
// ---------------------------------------------------------------------------
__global__ __launch_bounds__(256) void mas_tab_kernel(
    const unsigned int* __restrict__ diag_g, unsigned char* __restrict__ E_g)
{
    const int t  = threadIdx.x;        // entry row
    const int cg = blockIdx.x;         // chunk group of 16
    const int b  = blockIdx.y;
    const unsigned int* dg = diag_g + (size_t)b * (TY_ / 8) * 64;
    unsigned char* Eb = E_g + (size_t)b * (TY_ / 8) * 256;
    const int p = t >> 3;

    for (int k = 0; k < 16; ++k) {
        const int c = cg * 16 + k;
        unsigned long long W  = *(const unsigned long long*)&dg[c * 64 + 2 * p];
        unsigned long long Wl = p > 0
            ? *(const unsigned long long*)&dg[c * 64 + 2 * (p - 1)] : 0ULL;
        int ii = t;
#pragma unroll
        for (int jb = 7; jb >= 0; --jb) BT_STEP(jb)
        Eb[c * 256 + t] = (unsigned char)ii;
    }
}

// ---------------------------------------------------------------------------
// Kernel 2c: MAS backtrace via exit tables (unchanged).
// ---------------------------------------------------------------------------
__global__ __launch_bounds__(256) void mas_bt_kernel(
    const unsigned int* __restrict__ diag_g, const unsigned char* __restrict__ E_g,
    const int* __restrict__ xlen, const int* __restrict__ ylen,
    float* __restrict__ dr_out, int* __restrict__ idx_out)
{
    __shared__ unsigned char E[256 * 256];      // 64 KiB
    __shared__ unsigned char entry_s[256];
    __shared__ int rows_l[TY_];                 // 8 KiB
    __shared__ int cnt_l[TX_];                  // 1 KiB
    const int tid = threadIdx.x;
    const int b = blockIdx.x;
    const int x_len = xlen[b];
    const int y_len = ylen[b];

    cnt_l[tid] = 0;

    const uint4* srcE = (const uint4*)(E_g + (size_t)b * (TY_ / 8) * 256);
    uint4* dstE = (uint4*)E;
#pragma unroll
    for (int it = 0; it < 16; ++it)
        dstE[tid + it * 256] = srcE[tid + it * 256];
    __syncthreads();

    const unsigned int* dg = diag_g + (size_t)b * (TY_ / 8) * 64;
    int* ib = idx_out + (size_t)b * TY_;
    const int jc = (y_len - 1) >> 3;

    if (tid == 0) {
        int ii = x_len - 1;
        int p = ii >> 3;
        unsigned long long W  = *(const unsigned long long*)&dg[jc * 64 + 2 * p];
        unsigned long long Wl = p > 0
            ? *(const unsigned long long*)&dg[jc * 64 + 2 * (p - 1)] : 0ULL;
        for (int jb = (y_len - 1) & 7; jb >= 0; --jb) {
            int j = 8 * jc + jb;
            ib[j] = ii; rows_l[j] = ii;
            BT_STEP(jb)
        }
        int cur = ii;
        for (int c = jc - 1; c >= 0; --c) {
            entry_s[c] = (unsigned char)cur;
            cur = E[c * 256 + cur];
        }
    }
    __syncthreads();

    if (tid < jc) {
        const int c = tid;
        int ii = entry_s[c];
        int p = ii >> 3;
        unsigned long long W  = *(const unsigned long long*)&dg[c * 64 + 2 * p];
        unsigned long long Wl = p > 0
            ? *(const unsigned long long*)&dg[c * 64 + 2 * (p - 1)] : 0ULL;
        int r[8];
#pragma unroll
        for (int jb = 7; jb >= 0; --jb) {
            r[jb] = ii;
            BT_STEP(jb)
        }
        *reinterpret_cast<int4*>(&ib[8 * c])     = make_int4(r[0], r[1], r[2], r[3]);
        *reinterpret_cast<int4*>(&ib[8 * c + 4]) = make_int4(r[4], r[5], r[6], r[7]);
        *reinterpret_cast<int4*>(&rows_l[8 * c])     = make_int4(r[0], r[1], r[2], r[3]);
        *reinterpret_cast<int4*>(&rows_l[8 * c + 4]) = make_int4(r[4], r[5], r[6], r[7]);
    }
    __syncthreads();

    for (int t = tid; t < TY_; t += 256)
        if (t < y_len) atomicAdd(&cnt_l[rows_l[t]], 1);
    __syncthreads();
    dr_out[(size_t)b * TX_ + tid] = (float)cnt_l[tid];
}

// ---------------------------------------------------------------------------
// Kernel 3a: legacy dense emit (verified) — used when ws is too small and
// attn slot doubles as scratch (must be fully overwritten).
// ---------------------------------------------------------------------------
__global__ __launch_bounds__(256) void emit_kernel(
    const float* __restrict__ en, const int* __restrict__ ylen,
    const int* __restrict__ idx_in, float* __restrict__ o_en,
    float* __restrict__ attn)
{
    const int tid = threadIdx.x;
    const int b = blockIdx.x;
    const int r = blockIdx.y;
    const int y_len = ylen[b];
    const int* ib = idx_in + (size_t)b * TY_;

    if (r < 256) {
        const int x = r;
        float* out = attn + ((size_t)b * TX_ + x) * TY_;
        for (int t = tid; t < TY_; t += 256) {
            int ii = ib[t];
            out[t] = (t < y_len && ii == x) ? 1.f : 0.f;
        }
    } else {
        const int h = r - 256;
        __shared__ float enr[256];
        enr[tid] = en[((size_t)b * H_ + h) * TX_ + tid];
        __syncthreads();
        float* out = o_en + ((size_t)b * H_ + h) * TY_;
        for (int t = tid; t < TY_; t += 256) {
            int ii = ib[t];
            bool a = (t < y_len);
            int is = a ? ii : 0;
            out[t] = a ? enr[is] : 0.f;
        }
    }
}

// ---------------------------------------------------------------------------
// Kernel 3b: sparse emit — when logp_t/E live in d_ws, the attn slot is never
// scratched: it stays memset-zero, so we only scatter the ~y_len ones per
// batch (saves the 33.5 MB dense attn write). o_en stays DENSE (its slot
// holds diag scratch that must be overwritten).
// ---------------------------------------------------------------------------
__global__ __launch_bounds__(256) void emit_sparse_kernel(
    const float* __restrict__ en, const int* __restrict__ ylen,
    const int* __restrict__ idx_in, float* __restrict__ o_en,
    float* __restrict__ attn)
{
    const int tid = threadIdx.x;
    const int b = blockIdx.x;
    const int r = blockIdx.y;           // 0..255 = o_en rows, 256 = attn scatter
    const int y_len = ylen[b];
    const int* ib = idx_in + (size_t)b * TY_;

    if (r == 256) {
        float* ab = attn + (size_t)b * TX_ * TY_;
        for (int t = tid; t < TY_; t += 256)
            if (t < y_len) ab[(size_t)ib[t] * TY_ + t] = 1.f;
    } else {
        const int h = r;
        __shared__ float enr[256];
        enr[tid] = en[((size_t)b * H_ + h) * TX_ + tid];
        __syncthreads();
        float* out = o_en + ((size_t)b * H_ + h) * TY_;
        for (int t = tid; t < TY_; t += 256) {
            int ii = ib[t];
            bool a = (t < y_len);
            int is = a ? ii : 0;
            out[t] = a ? enr[is] : 0.f;
        }
    }
}

// ---------------------------------------------------------------------------
extern "C" void kernel_launch(void* const* d_in, const int* in_sizes, int n_in,
                              void* d_out, int out_size, void* d_ws, size_t ws_size,
                              hipStream_t stream)
{
    const float* en = (const float*)d_in[0];
    const float* mu = (const float*)d_in[1];
    const float* ls = (const float*)d_in[2];
    const float* y  = (const float*)d_in[3];
    const int* xl   = (const int*)d_in[4];
    const int* yl   = (const int*)d_in[5];

    float* o_en = (float*)d_out;                       // [16,256,2048]
    float* attn = o_en + (size_t)B_ * TX_ * TY_;       // [16,256,2048]
    float* dr   = attn + (size_t)B_ * TX_ * TY_;       // [16,256]
    float* logp = dr + (size_t)B_ * TX_;               // [16,256,2048]

    const size_t logp_t_bytes = (size_t)B_ * TX_ * TY_ * 4;      // 33.5 MB
    const size_t E_bytes      = (size_t)B_ * (TY_ / 8) * 256;    // 1 MB
    const size_t idx_bytes    = (size_t)B_ * TY_ * 4;            // 128 KB

    unsigned int* diag_g = (unsigned int*)o_en;        // diag scratch (1 MB)

    float* logp_t;
    unsigned char* E_g;
    int* idxArr;
    bool sparse;
    if (ws_size >= logp_t_bytes + E_bytes + idx_bytes) {
        // workspace path: attn slot never scratched -> sparse attn emit
        logp_t = (float*)d_ws;
        E_g    = (unsigned char*)d_ws + logp_t_bytes;
        idxArr = (int*)((char*)d_ws + logp_t_bytes + E_bytes);
        sparse = true;
    } else {
        // legacy (R4-verified) aliasing: logp_t/E in attn slot, dense emit
        logp_t = attn;
        E_g    = (unsigned char*)attn;
        idxArr = (int*)d_ws;
        sparse = false;
    }

    dim3 g1(2, 16, 16);
    logp_kernel<<<g1, 256, 0, stream>>>(mu, ls, y, logp, logp_t);

    mas_fwd_kernel<<<dim3(16), dim3(64), 0, stream>>>(logp_t, diag_g);
    mas_tab_kernel<<<dim3(16, 16), dim3(256), 0, stream>>>(diag_g, E_g);
    mas_bt_kernel<<<dim3(16), dim3(256), 0, stream>>>(diag_g, E_g, xl, yl, dr, idxArr);

    if (sparse) {
        dim3 g3(16, 257);
        emit_sparse_kernel<<<g3, 256, 0, stream>>>(en, yl, idxArr, o_en, attn);
    } else {
        dim3 g3(16, 512);
        emit_kernel<<<g3, 256, 0, stream>>>(en, yl, idxArr, o_en, attn);
    }
}

// Round 9
// 275.880 us; speedup vs baseline: 1.1037x; 1.0235x over previous
//
#include <hip/hip_runtime.h>
#include <hip/hip_bf16.h>
#include <cstdint>
#include <cstddef>

#define B_ 16
#define TX_ 256
#define TY_ 2048
#define C_ 80
#define H_ 256
#define NEG_ -1e9f
#define NEG_I (int)0xCE6E6B28   // bit pattern of -1e9f

// one backtrace step at column-in-chunk jb from row ii, using window pair W
// (rows 8p..8p+7) with fallback Wl (rows 8p-8..8p-1).
// Diag bit layout (4 independent carry-push chains in fwd): within each
// 32-bit word (4 rows), row r = byte r; column jb at bit (7-jb). In the u64
// W, rows 8p..8p+3 are the low word, 8p+4..8p+7 the high word, so the bit
// for row ii, col jb sits at ((ii&7)<<3) | (7-jb).
#define BT_STEP(JB)                                                           \
    {                                                                         \
        unsigned bit = ((unsigned)(W >> (((ii & 7) << 3)                      \
                                         | (7 - (JB)))) & 1u)                 \
                     & (unsigned)(ii > 0);                                    \
        ii -= (int)bit;                                                       \
        W = (bit && ((ii & 7) == 7)) ? Wl : W;                                \
    }

// ---------------------------------------------------------------------------
// Kernel 1: logp (unchanged, verified).
// ---------------------------------------------------------------------------
__global__ __launch_bounds__(256) void logp_kernel(
    const float* __restrict__ mu, const float* __restrict__ ls,
    const float* __restrict__ y, float* __restrict__ logp_out,
    float* __restrict__ logp_t)
{
    __shared__ float2 coef[16 * 80];
    __shared__ float  aux[16 * 80];
    __shared__ float  Kx[16];
    __shared__ float  yt[16 * 1028];

    const int tid = threadIdx.x;
    const int t0 = blockIdx.x * 1024;
    const int x0 = blockIdx.y * 16;
    const int b  = blockIdx.z;

    for (int i = tid; i < 16 * 80; i += 256) {
        int c = i >> 4, x = i & 15;
        float m = mu[(size_t)(b * C_ + c) * TX_ + x0 + x];
        float l = ls[(size_t)(b * C_ + c) * TX_ + x0 + x];
        float w = __expf(-2.f * l);
        coef[x * 80 + c] = make_float2(w, -2.f * m * w);
        aux[x * 80 + c]  = fmaf(m * m, w, l);
    }
    __syncthreads();
    if (tid < 16) {
        float s = 0.f;
        for (int c = 0; c < C_; ++c) s += aux[tid * 80 + c];
        Kx[tid] = -0.5f * s / (float)C_;
    }

    float acc[16][4];
#pragma unroll
    for (int x = 0; x < 16; ++x)
#pragma unroll
        for (int r = 0; r < 4; ++r) acc[x][r] = 0.f;

    const float4* y4 = (const float4*)y;
    for (int c0 = 0; c0 < C_; c0 += 16) {
        __syncthreads();
        for (int it = 0; it < 16; ++it) {
            int f = tid + it * 256;
            int t = f >> 2, k = f & 3;
            float4 v = y4[(size_t)(b * TY_ + t0 + t) * 20 + (c0 >> 2) + k];
            yt[(4 * k + 0) * 1028 + t] = v.x;
            yt[(4 * k + 1) * 1028 + t] = v.y;
            yt[(4 * k + 2) * 1028 + t] = v.z;
            yt[(4 * k + 3) * 1028 + t] = v.w;
        }
        __syncthreads();
        for (int cl = 0; cl < 16; ++cl) {
            const float4 yv = *reinterpret_cast<const float4*>(&yt[cl * 1028 + 4 * tid]);
            float4 y2 = make_float4(yv.x * yv.x, yv.y * yv.y, yv.z * yv.z, yv.w * yv.w);
#pragma unroll
            for (int x = 0; x < 16; ++x) {
                float2 f2 = coef[x * 80 + c0 + cl];
                acc[x][0] = fmaf(y2.x, f2.x, fmaf(yv.x, f2.y, acc[x][0]));
                acc[x][1] = fmaf(y2.y, f2.x, fmaf(yv.y, f2.y, acc[x][1]));
                acc[x][2] = fmaf(y2.z, f2.x, fmaf(yv.z, f2.y, acc[x][2]));
                acc[x][3] = fmaf(y2.w, f2.x, fmaf(yv.w, f2.y, acc[x][3]));
            }
        }
    }

#pragma unroll
    for (int x = 0; x < 16; ++x) {
        float kx = Kx[x];
#pragma unroll
        for (int r = 0; r < 4; ++r) acc[x][r] = fmaf(acc[x][r], -0.5f / (float)C_, kx);
        float4 out = make_float4(acc[x][0], acc[x][1], acc[x][2], acc[x][3]);
        *reinterpret_cast<float4*>(
            &logp_out[(size_t)(b * TX_ + x0 + x) * TY_ + t0 + 4 * tid]) = out;
    }
#pragma unroll
    for (int r = 0; r < 4; ++r) {
#pragma unroll
        for (int q = 0; q < 4; ++q) {
            float4 out = make_float4(acc[4 * q + 0][r], acc[4 * q + 1][r],
                                     acc[4 * q + 2][r], acc[4 * q + 3][r]);
            *reinterpret_cast<float4*>(
                &logp_t[(size_t)(b * TY_ + t0 + 4 * tid + r) * TX_ + x0 + 4 * q]) = out;
        }
    }
}

// ---------------------------------------------------------------------------
// Kernel 2a: MAS forward — R4-VERIFIED full inline asm scan (single wave per
// batch, stall-free schedule, 32-col prefetch in v32..v159, vmcnt(24)).
// ---------------------------------------------------------------------------
#define PROQ(A, Bq, Cq, Dq) \
    "global_load_dwordx4 " A ", %[vo], %[sb]\n\t" \
    "global_load_dwordx4 " Bq ", %[vo], %[sb] offset:0x400\n\t" \
    "global_load_dwordx4 " Cq ", %[vo], %[sb] offset:0x800\n\t" \
    "global_load_dwordx4 " Dq ", %[vo], %[sb] offset:0xC00\n\t" \
    "v_add_u32 %[vo], 0x1000, %[vo]\n\t"

#define ADDVO "v_add_u32 %[vo], 0x1000, %[vo]\n\t"

// SHU: sh register for THIS column; SHD: sh register produced for NEXT column.
#define COLN(RQ, R0, R1, R2, R3, SHU, SHD, OFF) \
    "v_cmp_gt_f32 vcc, " SHU ", %[v0]\n\t" \
    "v_cmp_gt_f32 s[20:21], %[v0], %[v1]\n\t" \
    "v_cmp_gt_f32 s[22:23], %[v1], %[v2]\n\t" \
    "v_cmp_gt_f32 s[24:25], %[v2], %[v3]\n\t" \
    "v_max_f32 %[v3], %[v2], %[v3]\n\t" \
    "v_max_f32 %[v2], %[v1], %[v2]\n\t" \
    "v_add_f32 %[v3], " R3 ", %[v3]\n\t" \
    "v_max_f32 %[v1], %[v0], %[v1]\n\t" \
    "v_max_f32 %[v0], " SHU ", %[v0]\n\t" \
    "v_mov_b32_dpp " SHD ", %[v3] wave_shr:1 row_mask:0xf bank_mask:0xf\n\t" \
    "v_add_f32 %[v2], " R2 ", %[v2]\n\t" \
    "v_add_f32 %[v1], " R1 ", %[v1]\n\t" \
    "v_add_f32 %[v0], " R0 ", %[v0]\n\t" \
    "v_addc_co_u32 %[a0], vcc, %[a0], %[a0], vcc\n\t" \
    "v_addc_co_u32 %[a1], s[20:21], %[a1], %[a1], s[20:21]\n\t" \
    "v_addc_co_u32 %[a2], s[22:23], %[a2], %[a2], s[22:23]\n\t" \
    "v_addc_co_u32 %[a3], s[24:25], %[a3], %[a3], s[24:25]\n\t" \
    "global_load_dwordx4 " RQ ", %[vo], %[sb] offset:" OFF "\n\t"

#define STOREBLK(OFFD) \
    "v_lshl_or_b32 v29, %[a1], 8, %[a0]\n\t" \
    "v_lshl_or_b32 v29, %[a2], 16, v29\n\t" \
    "v_lshl_or_b32 v29, %[a3], 24, v29\n\t" \
    "global_store_dword %[df], v29, %[db] offset:" OFFD "\n\t" \
    "v_mov_b32 %[a0], 0\n\t" \
    "v_mov_b32 %[a1], 0\n\t" \
    "v_mov_b32 %[a2], 0\n\t" \
    "v_mov_b32 %[a3], 0\n\t"

#define WAITG "s_waitcnt vmcnt(24)\n\t"

__global__ __launch_bounds__(64, 1) void mas_fwd_kernel(
    const float* __restrict__ logp_t, unsigned int* __restrict__ diag_g)
{
    const int lane = threadIdx.x;
    const int b = blockIdx.x;

    uint64_t sb = (uint64_t)(logp_t + (size_t)b * TY_ * TX_);
    uint64_t db = (uint64_t)(diag_g + (size_t)b * (TY_ / 8) * 64);
    unsigned vo = (unsigned)(lane * 16);   // voffset into logp_t (bytes)
    unsigned df = (unsigned)(lane * 4);    // voffset into diag (bytes)

    float v0 = (lane == 0) ? 0.f : NEG_, v1 = NEG_, v2 = NEG_, v3 = NEG_;
    unsigned a0 = 0, a1 = 0, a2 = 0, a3 = 0;

    asm volatile(
        // ---- sh ping-pong init (all lanes NEG; lane0 persists NEG) ----
        "v_mov_b32 v28, 0xce6e6b28\n\t"
        "v_mov_b32 v30, 0xce6e6b28\n\t"
        // ---- 32-column prologue fill (cols 0..31) ----
        PROQ("v[32:35]",   "v[36:39]",   "v[40:43]",   "v[44:47]")
        PROQ("v[48:51]",   "v[52:55]",   "v[56:59]",   "v[60:63]")
        PROQ("v[64:67]",   "v[68:71]",   "v[72:75]",   "v[76:79]")
        PROQ("v[80:83]",   "v[84:87]",   "v[88:91]",   "v[92:95]")
        PROQ("v[96:99]",   "v[100:103]", "v[104:107]", "v[108:111]")
        PROQ("v[112:115]", "v[116:119]", "v[120:123]", "v[124:127]")
        PROQ("v[128:131]", "v[132:135]", "v[136:139]", "v[140:143]")
        PROQ("v[144:147]", "v[148:151]", "v[152:155]", "v[156:159]")
        "s_mov_b32 s26, 64\n\t"
        "Lmas_%=:\n\t"
        // ---- group 0: cols +0..7 (buffer v32..v63) ----
        WAITG
        COLN("v[32:35]", "v32", "v33", "v34", "v35", "v28", "v30", "0")
        COLN("v[36:39]", "v36", "v37", "v38", "v39", "v30", "v28", "0x400")
        COLN("v[40:43]", "v40", "v41", "v42", "v43", "v28", "v30", "0x800")
        COLN("v[44:47]", "v44", "v45", "v46", "v47", "v30", "v28", "0xC00")
        ADDVO
        COLN("v[48:51]", "v48", "v49", "v50", "v51", "v28", "v30", "0")
        COLN("v[52:55]", "v52", "v53", "v54", "v55", "v30", "v28", "0x400")
        COLN("v[56:59]", "v56", "v57", "v58", "v59", "v28", "v30", "0x800")
        COLN("v[60:63]", "v60", "v61", "v62", "v63", "v30", "v28", "0xC00")
        ADDVO
        STOREBLK("0")
        // ---- group 1: cols +8..15 (v64..v95) ----
        WAITG
        COLN("v[64:67]", "v64", "v65", "v66", "v67", "v28", "v30", "0")
        COLN("v[68:71]", "v68", "v69", "v70", "v71", "v30", "v28", "0x400")
        COLN("v[72:75]", "v72", "v73", "v74", "v75", "v28", "v30", "0x800")
        COLN("v[76:79]", "v76", "v77", "v78", "v79", "v30", "v28", "0xC00")
        ADDVO
        COLN("v[80:83]", "v80", "v81", "v82", "v83", "v28", "v30", "0")
        COLN("v[84:87]", "v84", "v85", "v86", "v87", "v30", "v28", "0x400")
        COLN("v[88:91]", "v88", "v89", "v90", "v91", "v28", "v30", "0x800")
        COLN("v[92:95]", "v92", "v93", "v94", "v95", "v30", "v28", "0xC00")
        ADDVO
        STOREBLK("0x100")
        // ---- group 2: cols +16..23 (v96..v127) ----
        WAITG
        COLN("v[96:99]",   "v96",  "v97",  "v98",  "v99",  "v28", "v30", "0")
        COLN("v[100:103]", "v100", "v101", "v102", "v103", "v30", "v28", "0x400")
        COLN("v[104:107]", "v104", "v105", "v106", "v107", "v28", "v30", "0x800")
        COLN("v[108:111]", "v108", "v109", "v110", "v111", "v30", "v28", "0xC00")
        ADDVO
        COLN("v[112:115]", "v112", "v113", "v114", "v115", "v28", "v30", "0")
        COLN("v[116:119]", "v116", "v117", "v118", "v119", "v30", "v28", "0x400")
        COLN("v[120:123]", "v120", "v121", "v122", "v123", "v28", "v30", "0x800")
        COLN("v[124:127]", "v124", "v125", "v126", "v127", "v30", "v28", "0xC00")
        ADDVO
        STOREBLK("0x200")
        // ---- group 3: cols +24..31 (v128..v159) ----
        WAITG
        COLN("v[128:131]", "v128", "v129", "v130", "v131", "v28", "v30", "0")
        COLN("v[132:135]", "v132", "v133", "v134", "v135", "v30", "v28", "0x400")
        COLN("v[136:139]", "v136", "v137", "v138", "v139", "v28", "v30", "0x800")
        COLN("v[140:143]", "v140", "v141", "v142", "v143", "v30", "v28", "0xC00")
        ADDVO
        COLN("v[144:147]", "v144", "v145", "v146", "v147", "v28", "v30", "0")
        COLN("v[148:151]", "v148", "v149", "v150", "v151", "v30", "v28", "0x400")
        COLN("v[152:155]", "v152", "v153", "v154", "v155", "v28", "v30", "0x800")
        COLN("v[156:159]", "v156", "v157", "v158", "v159", "v30", "v28", "0xC00")
        ADDVO
        STOREBLK("0x300")
        "v_add_u32 %[df], 0x400, %[df]\n\t"
        "s_sub_u32 s26, s26, 1\n\t"
        "s_cmp_lg_u32 s26, 0\n\t"
        "s_cbranch_scc1 Lmas_%=\n\t"
        : [v0]"+v"(v0), [v1]"+v"(v1), [v2]"+v"(v2), [v3]"+v"(v3),
          [a0]"+v"(a0), [a1]"+v"(a1), [a2]"+v"(a2), [a3]"+v"(a3),
          [vo]"+v"(vo), [df]"+v"(df)
        : [sb]"s"(sb), [db]"s"(db)
        : "vcc", "scc", "memory",
          "s20","s21","s22","s23","s24","s25","s26",
          "v28","v29","v30",
          "v32","v33","v34","v35","v36","v37","v38","v39",
          "v40","v41","v42","v43","v44","v45","v46","v47",
          "v48","v49","v50","v51","v52","v53","v54","v55",
          "v56","v57","v58","v59","v60","v61","v62","v63",
          "v64","v65","v66","v67","v68","v69","v70","v71",
          "v72","v73","v74","v75","v76","v77","v78","v79",
          "v80","v81","v82","v83","v84","v85","v86","v87",
          "v88","v89","v90","v91","v92","v93","v94","v95",
          "v96","v97","v98","v99","v100","v101","v102","v103",
          "v104","v105","v106","v107","v108","v109","v110","v111",
          "v112","v113","v114","v115","v116","v117","v118","v119",
          "v120","v121","v122","v123","v124","v125","v126","v127",
          "v128","v129","v130","v131","v132","v133","v134","v135",
          "v136","v137","v138","v139","v140","v141","v142","v143",
          "v144","v145","v146","v147","v148","v149","v150","v151",
          "v152","v153","v154","v155","v156","v157","v158","v159");
    // NOTE: tail loads (cols 2048..2079) read past this batch's logp_t rows;
    // that memory is still inside the surrounding buffer -> harmless.
}

// ---------------------------------------------------------------------------
// Kernel 2b: exit-table build + LEVEL-2 composition.
// E_c[i] = row after walking chunk c (8 cols) entered at row i (verified).
// NEW: E2[cg][i] = row after walking 16 chunks (cg*16+15 .. cg*16), i.e.
// E[16cg] ∘ ... ∘ E[16cg+15], built via 4KB LDS stage + 16 chained lookups.
// ---------------------------------------------------------------------------
__global__ __launch_bounds__(256) void mas_tab_kernel(
    const unsigned int* __restrict__ diag_g, unsigned char* __restrict__ E_g,
    unsigned char* __restrict__ E2_g)
{
    __shared__ unsigned char El[16][256];
    const int t  = threadIdx.x;        // entry row
    const int cg = blockIdx.x;         // chunk group of 16
    const int b  = blockIdx.y;
    const unsigned int* dg = diag_g + (size_t)b * (TY_ / 8) * 64;
    unsigned char* Eb = E_g + (size_t)b * (TY_ / 8) * 256;
    const int p = t >> 3;

    for (int k = 0; k < 16; ++k) {
        const int c = cg * 16 + k;
        unsigned long long W  = *(const unsigned long long*)&dg[c * 64 + 2 * p];
        unsigned long long Wl = p > 0
            ? *(const unsigned long long*)&dg[c * 64 + 2 * (p - 1)] : 0ULL;
        int ii = t;
#pragma unroll
        for (int jb = 7; jb >= 0; --jb) BT_STEP(jb)
        Eb[c * 256 + t] = (unsigned char)ii;
        El[k][t] = (unsigned char)ii;
    }
    __syncthreads();
    // compose: enter chunk cg*16+15 at row t, walk down through chunk cg*16
    int ii = t;
#pragma unroll
    for (int k = 15; k >= 0; --k) ii = El[k][ii];
    E2_g[((size_t)b * 16 + cg) * 256 + t] = (unsigned char)ii;
}

// ---------------------------------------------------------------------------
// Kernel 2c: MAS backtrace via 2-LEVEL exit tables. Serial chain is now
// partial-chunk bit-walk (<=8) + <=15 single-chunk E steps + <=15 E2 steps
// (~38 dependent LDS reads vs 263 before). Per-cg 16-chunk expansion runs
// on 16 parallel threads; emission unchanged (verified).
// ---------------------------------------------------------------------------
__global__ __launch_bounds__(256) void mas_bt_kernel(
    const unsigned int* __restrict__ diag_g, const unsigned char* __restrict__ E_g,
    const unsigned char* __restrict__ E2_g,
    const int* __restrict__ xlen, const int* __restrict__ ylen,
    float* __restrict__ dr_out, int* __restrict__ idx_out)
{
    __shared__ unsigned char E[256 * 256];      // 64 KiB
    __shared__ unsigned char E2l[16 * 256];     // 4 KiB
    __shared__ unsigned char entry_s[256];
    __shared__ unsigned char cg_entry[16];
    __shared__ int rows_l[TY_];                 // 8 KiB
    __shared__ int cnt_l[TX_];                  // 1 KiB
    const int tid = threadIdx.x;
    const int b = blockIdx.x;
    const int x_len = xlen[b];
    const int y_len = ylen[b];

    cnt_l[tid] = 0;

    const uint4* srcE = (const uint4*)(E_g + (size_t)b * (TY_ / 8) * 256);
    uint4* dstE = (uint4*)E;
#pragma unroll
    for (int it = 0; it < 16; ++it)
        dstE[tid + it * 256] = srcE[tid + it * 256];
    const uint4* srcE2 = (const uint4*)(E2_g + (size_t)b * 16 * 256);
    ((uint4*)E2l)[tid] = srcE2[tid];            // 256 * 16B = 4 KiB
    __syncthreads();

    const unsigned int* dg = diag_g + (size_t)b * (TY_ / 8) * 64;
    int* ib = idx_out + (size_t)b * TY_;
    const int jc = (y_len - 1) >> 3;            // partial chunk index
    const int cg0 = jc >> 4;                    // cg containing partial chunk

    if (tid == 0) {
        // partial top chunk (columns y_len-1 .. 8*jc), serial <=8 steps
        int ii = x_len - 1;
        int p = ii >> 3;
        unsigned long long W  = *(const unsigned long long*)&dg[jc * 64 + 2 * p];
        unsigned long long Wl = p > 0
            ? *(const unsigned long long*)&dg[jc * 64 + 2 * (p - 1)] : 0ULL;
        for (int jb = (y_len - 1) & 7; jb >= 0; --jb) {
            int j = 8 * jc + jb;
            ib[j] = ii; rows_l[j] = ii;
            BT_STEP(jb)
        }
        // single-chunk walk down to the cg boundary (<=15 dependent reads)
        int cur = ii;
        for (int c = jc - 1; c >= cg0 * 16; --c) {
            entry_s[c] = (unsigned char)cur;
            cur = E[c * 256 + cur];
        }
        // level-2 walk over full cgs (<=15 dependent reads)
        for (int cg = cg0 - 1; cg >= 0; --cg) {
            cg_entry[cg] = (unsigned char)cur;
            cur = E2l[cg * 256 + cur];
        }
    }
    __syncthreads();

    // per-cg expansion: 16 threads, 16 dependent reads each (parallel)
    if (tid < cg0) {
        int cur = cg_entry[tid];
        for (int k = 15; k >= 0; --k) {
            int c = tid * 16 + k;
            entry_s[c] = (unsigned char)cur;
            cur = E[c * 256 + cur];
        }
    }
    __syncthreads();

    // parallel emission: one thread per full chunk (verified)
    if (tid < jc) {
        const int c = tid;
        int ii = entry_s[c];
        int p = ii >> 3;
        unsigned long long W  = *(const unsigned long long*)&dg[c * 64 + 2 * p];
        unsigned long long Wl = p > 0
            ? *(const unsigned long long*)&dg[c * 64 + 2 * (p - 1)] : 0ULL;
        int r[8];
#pragma unroll
        for (int jb = 7; jb >= 0; --jb) {
            r[jb] = ii;
            BT_STEP(jb)
        }
        *reinterpret_cast<int4*>(&ib[8 * c])     = make_int4(r[0], r[1], r[2], r[3]);
        *reinterpret_cast<int4*>(&ib[8 * c + 4]) = make_int4(r[4], r[5], r[6], r[7]);
        *reinterpret_cast<int4*>(&rows_l[8 * c])     = make_int4(r[0], r[1], r[2], r[3]);
        *reinterpret_cast<int4*>(&rows_l[8 * c + 4]) = make_int4(r[4], r[5], r[6], r[7]);
    }
    __syncthreads();

    // dr[i] = #{ j < y_len : row(j) == i }
    for (int t = tid; t < TY_; t += 256)
        if (t < y_len) atomicAdd(&cnt_l[rows_l[t]], 1);
    __syncthreads();
    dr_out[(size_t)b * TX_ + tid] = (float)cnt_l[tid];
}

// ---------------------------------------------------------------------------
// Kernel 3a: legacy dense emit (verified) — used when ws is too small and
// attn slot doubles as scratch (must be fully overwritten).
// ---------------------------------------------------------------------------
__global__ __launch_bounds__(256) void emit_kernel(
    const float* __restrict__ en, const int* __restrict__ ylen,
    const int* __restrict__ idx_in, float* __restrict__ o_en,
    float* __restrict__ attn)
{
    const int tid = threadIdx.x;
    const int b = blockIdx.x;
    const int r = blockIdx.y;
    const int y_len = ylen[b];
    const int* ib = idx_in + (size_t)b * TY_;

    if (r < 256) {
        const int x = r;
        float* out = attn + ((size_t)b * TX_ + x) * TY_;
        for (int t = tid; t < TY_; t += 256) {
            int ii = ib[t];
            out[t] = (t < y_len && ii == x) ? 1.f : 0.f;
        }
    } else {
        const int h = r - 256;
        __shared__ float enr[256];
        enr[tid] = en[((size_t)b * H_ + h) * TX_ + tid];
        __syncthreads();
        float* out = o_en + ((size_t)b * H_ + h) * TY_;
        for (int t = tid; t < TY_; t += 256) {
            int ii = ib[t];
            bool a = (t < y_len);
            int is = a ? ii : 0;
            out[t] = a ? enr[is] : 0.f;
        }
    }
}

// ---------------------------------------------------------------------------
// Kernel 3b: sparse emit — when logp_t/E live in d_ws, the attn slot is never
// scratched: it stays memset-zero, so we only scatter the ~y_len ones per
// batch. o_en stays DENSE (its slot holds diag/E2 scratch).
// ---------------------------------------------------------------------------
__global__ __launch_bounds__(256) void emit_sparse_kernel(
    const float* __restrict__ en, const int* __restrict__ ylen,
    const int* __restrict__ idx_in, float* __restrict__ o_en,
    float* __restrict__ attn)
{
    const int tid = threadIdx.x;
    const int b = blockIdx.x;
    const int r = blockIdx.y;           // 0..255 = o_en rows, 256 = attn scatter
    const int y_len = ylen[b];
    const int* ib = idx_in + (size_t)b * TY_;

    if (r == 256) {
        float* ab = attn + (size_t)b * TX_ * TY_;
        for (int t = tid; t < TY_; t += 256)
            if (t < y_len) ab[(size_t)ib[t] * TY_ + t] = 1.f;
    } else {
        const int h = r;
        __shared__ float enr[256];
        enr[tid] = en[((size_t)b * H_ + h) * TX_ + tid];
        __syncthreads();
        float* out = o_en + ((size_t)b * H_ + h) * TY_;
        for (int t = tid; t < TY_; t += 256) {
            int ii = ib[t];
            bool a = (t < y_len);
            int is = a ? ii : 0;
            out[t] = a ? enr[is] : 0.f;
        }
    }
}

// ---------------------------------------------------------------------------
extern "C" void kernel_launch(void* const* d_in, const int* in_sizes, int n_in,
                              void* d_out, int out_size, void* d_ws, size_t ws_size,
                              hipStream_t stream)
{
    const float* en = (const float*)d_in[0];
    const float* mu = (const float*)d_in[1];
    const float* ls = (const float*)d_in[2];
    const float* y  = (const float*)d_in[3];
    const int* xl   = (const int*)d_in[4];
    const int* yl   = (const int*)d_in[5];

    float* o_en = (float*)d_out;                       // [16,256,2048]
    float* attn = o_en + (size_t)B_ * TX_ * TY_;       // [16,256,2048]
    float* dr   = attn + (size_t)B_ * TX_ * TY_;       // [16,256]
    float* logp = dr + (size_t)B_ * TX_;               // [16,256,2048]

    const size_t logp_t_bytes = (size_t)B_ * TX_ * TY_ * 4;      // 33.5 MB
    const size_t E_bytes      = (size_t)B_ * (TY_ / 8) * 256;    // 1 MB
    const size_t idx_bytes    = (size_t)B_ * TY_ * 4;            // 128 KB

    unsigned int* diag_g = (unsigned int*)o_en;        // diag scratch (1 MB)
    // E2 scratch (64 KB) at o_en + 2 MB (o_en slot overwritten by emit last)
    unsigned char* E2_g = (unsigned char*)o_en + (1u << 21);

    float* logp_t;
    unsigned char* E_g;
    int* idxArr;
    bool sparse;
    if (ws_size >= logp_t_bytes + E_bytes + idx_bytes) {
        // workspace path: attn slot never scratched -> sparse attn emit
        logp_t = (float*)d_ws;
        E_g    = (unsigned char*)d_ws + logp_t_bytes;
        idxArr = (int*)((char*)d_ws + logp_t_bytes + E_bytes);
        sparse = true;
    } else {
        // legacy (R4-verified) aliasing: logp_t/E in attn slot, dense emit
        logp_t = attn;
        E_g    = (unsigned char*)attn;
        idxArr = (int*)d_ws;
        sparse = false;
    }

    dim3 g1(2, 16, 16);
    logp_kernel<<<g1, 256, 0, stream>>>(mu, ls, y, logp, logp_t);

    mas_fwd_kernel<<<dim3(16), dim3(64), 0, stream>>>(logp_t, diag_g);
    mas_tab_kernel<<<dim3(16, 16), dim3(256), 0, stream>>>(diag_g, E_g, E2_g);
    mas_bt_kernel<<<dim3(16), dim3(256), 0, stream>>>(diag_g, E_g, E2_g,
                                                      xl, yl, dr, idxArr);

    if (sparse) {
        dim3 g3(16, 257);
        emit_sparse_kernel<<<g3, 256, 0, stream>>>(en, yl, idxArr, o_en, attn);
    } else {
        dim3 g3(16, 512);
        emit_kernel<<<g3, 256, 0, stream>>>(en, yl, idxArr, o_en, attn);
    }
}